// Round 6
// baseline (352.984 us; speedup 1.0000x reference)
//
#include <hip/hip_runtime.h>
#include <cstddef>

#define DEV static __device__ __forceinline__

typedef float f32x4 __attribute__((ext_vector_type(4)));
typedef __bf16 bf16x8 __attribute__((ext_vector_type(8)));
typedef __bf16 bf16x4v __attribute__((ext_vector_type(4)));
typedef unsigned short u16x8 __attribute__((ext_vector_type(8)));
typedef unsigned short u16x4 __attribute__((ext_vector_type(4)));
typedef unsigned u32x2 __attribute__((ext_vector_type(2)));
typedef unsigned u32x4 __attribute__((ext_vector_type(4)));
typedef _Float16 f16;
typedef _Float16 f16x4 __attribute__((ext_vector_type(4)));

constexpr int BB = 2, LL = 2048, DM = 1024, NH = 16, DK = 64;
constexpr float LOG2E = 1.44269504f;

DEV unsigned short f2bf(float f) {
  unsigned u = __builtin_bit_cast(unsigned, f);
  u += 0x7fffu + ((u >> 16) & 1u);  // RNE
  return (unsigned short)(u >> 16);
}
DEV u16x4 cvt4(f32x4 v) {  // packed f32x4 -> bf16x4
  bf16x4v b = __builtin_convertvector(v, bf16x4v);
  return __builtin_bit_cast(u16x4, b);
}
DEV bf16x8 asbf(u16x8 v) { return __builtin_bit_cast(bf16x8, v); }
DEV f32x4 mfma16(u16x8 a, u16x8 b, f32x4 c) {
  return __builtin_amdgcn_mfma_f32_16x16x32_bf16(asbf(a), asbf(b), c, 0, 0, 0);
}
#if __has_builtin(__builtin_amdgcn_exp2f)
DEV float fexp2(float x) { return __builtin_amdgcn_exp2f(x); }
#else
DEV float fexp2(float x) { return exp2f(x); }
#endif
// cross-lane 16/32-row swaps (gfx950): used to rebuild PV fragments in-register
DEV void swap32(unsigned& a, unsigned& b) {
#if __has_builtin(__builtin_amdgcn_permlane32_swap)
  u32x2 r = __builtin_amdgcn_permlane32_swap(a, b, false, false);
  a = r[0]; b = r[1];
#else
  asm("v_permlane32_swap_b32 %0, %1" : "+v"(a), "+v"(b));
#endif
}
DEV void swap16(unsigned& a, unsigned& b) {
#if __has_builtin(__builtin_amdgcn_permlane16_swap)
  u32x2 r = __builtin_amdgcn_permlane16_swap(a, b, false, false);
  a = r[0]; b = r[1];
#else
  asm("v_permlane16_swap_b32 %0, %1" : "+v"(a), "+v"(b));
#endif
}
// async global->LDS, 16B/lane; lds dest wave-uniform base (+lane*16 by HW)
DEV void g2lds16(const void* g, void* l) {
  __builtin_amdgcn_global_load_lds(
      (const __attribute__((address_space(1))) unsigned int*)g,
      (__attribute__((address_space(3))) unsigned int*)l, 16, 0, 0);
}

// ---------------------------------------------------------------------------
// prep_all: ALL preprocessing in one launch.
// Flat grid, block ranges:
//  [0,4096):      prep_w  — transpose+cvt 4 weight mats -> bf16 W^T[N][K]
//  [4096,12288):  prep_bm — bias/mask -> f16 exp2-domain, MFMA-fragment order
//  [12288,18432): prep_cvt — q/k/v fp32 -> bf16
// ---------------------------------------------------------------------------
__global__ __launch_bounds__(256) void prep_all(
    const float* __restrict__ w0, const float* __restrict__ w1,
    const float* __restrict__ w2, const float* __restrict__ w3,
    unsigned short* __restrict__ wT, const int* __restrict__ mask,
    const float* __restrict__ bias, f16* __restrict__ bmf,
    const float* __restrict__ s0, const float* __restrict__ s1,
    const float* __restrict__ s2, unsigned short* __restrict__ qkvb) {
  int f = blockIdx.x, t = threadIdx.x;
  if (f < 4096) {  // ---- prep_w
    __shared__ float tile[32][33];
    int z = f >> 10, rem = f & 1023;
    int k0 = (rem >> 5) * 32, n0 = (rem & 31) * 32;
    const float* W = (z == 0) ? w0 : (z == 1) ? w1 : (z == 2) ? w2 : w3;
    unsigned short* out = wT + (size_t)z * DM * DM;
    int tx = t & 31, ty = t >> 5;
#pragma unroll
    for (int p = 0; p < 4; p++)
      tile[ty + 8 * p][tx] = W[(size_t)(k0 + ty + 8 * p) * DM + n0 + tx];
    __syncthreads();
#pragma unroll
    for (int p = 0; p < 4; p++)
      out[(size_t)(n0 + ty + 8 * p) * DM + k0 + tx] = f2bf(tile[tx][ty + 8 * p]);
  } else if (f < 12288) {  // ---- prep_bm (fragment order)
    int f2 = f - 4096;
    int w = t >> 6, lane = t & 63;
    int bq = f2 >> 5;               // b*128 + qt
    int kt = (f2 & 31) * 4 + w;
    int b = bq >> 7, qt = bq & 127;
    int q = qt * 16 + (lane & 15);
    int k = kt * 16 + (lane >> 4) * 4;
    size_t src = ((size_t)b * LL + q) * LL + k;
    int4 mk = *(const int4*)(mask + src);
    float4 bs = *(const float4*)(bias + src);
    f16x4 o;
    o[0] = (f16)((mk.x == 0 ? -10000.f : bs.x) * LOG2E);
    o[1] = (f16)((mk.y == 0 ? -10000.f : bs.y) * LOG2E);
    o[2] = (f16)((mk.z == 0 ? -10000.f : bs.z) * LOG2E);
    o[3] = (f16)((mk.w == 0 ? -10000.f : bs.w) * LOG2E);
    *(f16x4*)(bmf + ((size_t)bq * 128 + kt) * 256 + lane * 4) = o;
  } else {  // ---- prep_cvt
    int f3 = f - 12288;
    int z = f3 >> 11;
    const float* src = (z == 0) ? s0 : (z == 1) ? s1 : s2;
    size_t i = ((size_t)(f3 & 2047) * 256 + t) * 8;
    float4 a = *(const float4*)(src + i);
    float4 b = *(const float4*)(src + i + 4);
    u16x8 o;
    o[0] = f2bf(a.x); o[1] = f2bf(a.y); o[2] = f2bf(a.z); o[3] = f2bf(a.w);
    o[4] = f2bf(b.x); o[5] = f2bf(b.y); o[6] = f2bf(b.z); o[7] = f2bf(b.w);
    *(u16x8*)(qkvb + (size_t)z * (size_t)(BB * LL) * DM + i) = o;
  }
}

// ---------------------------------------------------------------------------
// GEMM core, m97 structure: 128x128 tile, BK=64, single-buffered 32 KB LDS,
// global_load_lds staging, 2 barriers/iter. Swizzle on the GLOBAL address
// side (gsw); LDS dest is linear base+lane*16.
// ---------------------------------------------------------------------------
template <int KITERS>
DEV void gemm_core(const unsigned short* __restrict__ A,
                   const unsigned short* __restrict__ BT,
                   unsigned short* Al, unsigned short* Bl,
                   int m0, int n0, int k0beg, int t, f32x4 (&acc)[4][4]) {
  int lane = t & 63, c = lane & 15, qd = lane >> 4;
  int w = t >> 6, wm = w >> 1, wn = w & 1;
  int r0 = t >> 3;               // 0..31; rows r0+32p keep same low 3 bits
  int gsw = (t & 7) ^ (r0 & 7);  // swizzled col-group for this thread

#pragma unroll 1
  for (int kk = 0; kk < KITERS; ++kk) {
    int k0 = k0beg + kk * 64;
#pragma unroll
    for (int p = 0; p < 4; ++p) {  // DMA: wave-uniform LDS base + lane*16
      g2lds16(&A[(size_t)(m0 + 32 * p + r0) * DM + k0 + 8 * gsw],
              &Al[p * 2048 + w * 512]);
      g2lds16(&BT[(size_t)(n0 + 32 * p + r0) * DM + k0 + 8 * gsw],
              &Bl[p * 2048 + w * 512]);
    }
    __syncthreads();  // drain DMA (vmcnt(0) folded into barrier)
#pragma unroll
    for (int ks = 0; ks < 2; ++ks) {
      u16x8 af[4], bfr[4];
#pragma unroll
      for (int mt = 0; mt < 4; ++mt)
        af[mt] = *(const u16x8*)&Al[(64 * wm + 16 * mt + c) * 64 +
                                    (((4 * ks + qd) ^ (c & 7)) << 3)];
#pragma unroll
      for (int nt = 0; nt < 4; ++nt)
        bfr[nt] = *(const u16x8*)&Bl[(64 * wn + 16 * nt + c) * 64 +
                                     (((4 * ks + qd) ^ (c & 7)) << 3)];
#pragma unroll
      for (int mt = 0; mt < 4; ++mt)
#pragma unroll
        for (int nt = 0; nt < 4; ++nt)
          acc[mt][nt] = mfma16(af[mt], bfr[nt], acc[mt][nt]);
    }
    __syncthreads();  // all reads done before next stage overwrites
  }
}

// fused q/k/v projections: 1-D grid 768, XCD-chunked swizzle (768%8==0).
__global__ __launch_bounds__(256, 3) void proj_gemm(
    const unsigned short* __restrict__ qkvb, const unsigned short* __restrict__ wT,
    unsigned short* __restrict__ qh, unsigned short* __restrict__ kh,
    unsigned short* __restrict__ vT) {
  __shared__ unsigned short Al[128 * 64];  // 16 KiB
  __shared__ unsigned short Bl[128 * 64];  // 16 KiB
  int o = blockIdx.x;
  int wg = (o & 7) * 96 + (o >> 3);  // bijective: 96 consecutive wgs per XCD
  int z = wg >> 8, rem = wg & 255;
  int m0 = (rem >> 3) * 128, n0 = (rem & 7) * 128;
  const unsigned short* A = qkvb + (size_t)z * BB * LL * DM;
  const unsigned short* BT = wT + (size_t)z * DM * DM;
  int t = threadIdx.x, lane = t & 63, c = lane & 15, qd = lane >> 4;
  int w = t >> 6, wm = w >> 1, wn = w & 1;
  f32x4 acc[4][4] = {};
  gemm_core<DM / 64>(A, BT, Al, Bl, m0, n0, 0, t, acc);

  if (z == 2) {  // V: per-head transposed vT[b][h][d][l]
#pragma unroll
    for (int mt = 0; mt < 4; ++mt)
#pragma unroll
      for (int nt = 0; nt < 4; ++nt) {
        int n = n0 + 64 * wn + 16 * nt + c;
        int h = n >> 6, d = n & 63;
        int m = m0 + 64 * wm + 16 * mt + 4 * qd;  // i=0..3 consecutive in l
        int b = m >> 11, l = m & 2047;
        *(u16x4*)&vT[(((size_t)b * NH + h) * DK + d) * LL + l] = cvt4(acc[mt][nt]);
      }
  } else {  // Q/K: head-split [b][h][l][d]; Q carries temperature*log2e
    unsigned short* Ch = z ? kh : qh;
    float scale = z ? 1.0f : 0.125f * LOG2E;
#pragma unroll
    for (int mt = 0; mt < 4; ++mt)
#pragma unroll
      for (int nt = 0; nt < 4; ++nt) {
        int n = n0 + 64 * wn + 16 * nt + c;
        int h = n >> 6, d = n & 63;
#pragma unroll
        for (int i = 0; i < 4; ++i) {
          int m = m0 + 64 * wm + 16 * mt + 4 * qd + i;
          int b = m >> 11, l = m & 2047;
          Ch[(((size_t)b * NH + h) * LL + l) * DK + d] = f2bf(acc[mt][nt][i] * scale);
        }
      }
  }
}

// final fc: single-K (16 iters), direct f32 stores, no atomics/zeroing.
// 1-D grid 256, XCD-chunked swizzle (256%8==0).
__global__ __launch_bounds__(256, 3) void fc_gemm(const unsigned short* __restrict__ A,
                                                  const unsigned short* __restrict__ BT,
                                                  float* __restrict__ C) {
  __shared__ unsigned short Al[128 * 64];
  __shared__ unsigned short Bl[128 * 64];
  int o = blockIdx.x;
  int wg = (o & 7) * 32 + (o >> 3);  // 32 consecutive wgs per XCD
  int m0 = (wg >> 3) * 128, n0 = (wg & 7) * 128;
  int t = threadIdx.x, lane = t & 63, c = lane & 15, qd = lane >> 4;
  int w = t >> 6, wm = w >> 1, wn = w & 1;
  f32x4 acc[4][4] = {};
  gemm_core<DM / 64>(A, BT, Al, Bl, m0, n0, 0, t, acc);
#pragma unroll
  for (int mt = 0; mt < 4; ++mt)
#pragma unroll
    for (int nt = 0; nt < 4; ++nt) {
      int n = n0 + 64 * wn + 16 * nt + c;
#pragma unroll
      for (int i = 0; i < 4; ++i) {
        int m = m0 + 64 * wm + 16 * mt + 4 * qd + i;
        C[(size_t)m * DM + n] = acc[mt][nt][i];
      }
    }
}

// ---------------------------------------------------------------------------
// attn: NO LDS, NO BARRIERS. All operands live in global memory in exact
// MFMA-fragment layout (kh=[l][d], vT=[d][l], qh=[l][d], bmf frag-ordered),
// so fragments load global->VGPR directly (64B-segment coalesced, L2-hit via
// XCD swizzle). TK=32/iter; register ping-pong (A/B sets) one iteration
// ahead -> compiler emits counted vmcnt waits; every wave free-runs.
// 4 waves x 32 q = 128 q/block; grid 512 = 2 blk/CU = 8 waves/CU.
//  - bias folds into QK^T accumulator init (free C-in add).
//  - P^T rebuilt in-register (cvt4 + permlane32/16_swap).
//  - li via ones-row MFMA; s_setprio(1) around MFMA clusters.
// ---------------------------------------------------------------------------
__global__ __launch_bounds__(256, 2) void attn_kern(
    const unsigned short* __restrict__ qh, const unsigned short* __restrict__ kh,
    const unsigned short* __restrict__ vT, const f16* __restrict__ bmf,
    unsigned short* __restrict__ O) {
  int t = threadIdx.x, w = t >> 6, lane = t & 63, c = lane & 15, qd = lane >> 4;
  int o = blockIdx.x;
  int wg = (o & 7) * 64 + (o >> 3);  // bijective XCD chunking (512%8==0):
  int x = wg & 15, h = (wg >> 4) & 15, b = wg >> 8;  // 4 heads per XCD -> L2
  int q0 = x * 128;
  const unsigned short* Q = qh + (((size_t)b * NH + h) * LL + q0) * DK;
  const unsigned short* K = kh + ((size_t)b * NH + h) * LL * DK;
  const unsigned short* V = vT + ((size_t)b * NH + h) * DK * LL;
  // fragment-ordered bias: wave w owns q-tiles x*8 + 2w + nt
  const f16* BMF0 = bmf + (((size_t)b * 128 + x * 8 + 2 * w) * 128) * 256 + lane * 4;
  const f16* BMF1 = BMF0 + (size_t)128 * 256;

  // Q fragments: direct per-lane loads (rows 32w+16nt+c, cols 8(4ks+qd))
  u16x8 qf[2][2];
#pragma unroll
  for (int nt = 0; nt < 2; ++nt)
#pragma unroll
    for (int ks = 0; ks < 2; ++ks)
      qf[nt][ks] =
          *(const u16x8*)&Q[(size_t)(32 * w + 16 * nt + c) * DK + 8 * (4 * ks + qd)];

  const u16x8 ones = {0x3F80, 0x3F80, 0x3F80, 0x3F80,
                      0x3F80, 0x3F80, 0x3F80, 0x3F80};  // bf16 1.0
  f32x4 lacc[2] = {};     // [nt] li accumulators via ones-MFMA
  f32x4 oacc[4][2] = {};  // [dt][nt]

  // per-iter fragment sets (TK=32): K [mt*2+ks], V [dt], bias [nt*2+mt]
  u16x8 kfA[4], vfA[4], kfB[4], vfB[4];
  f16x4 bA[4], bB[4];

  auto loadset = [&](int it, u16x8 (&kf)[4], u16x8 (&vf)[4], f16x4 (&bb)[4]) {
    const unsigned short* Kt = K + (size_t)it * 32 * DK;
    const unsigned short* Vt = V + (size_t)it * 32;
#pragma unroll
    for (int mt = 0; mt < 2; ++mt)
#pragma unroll
      for (int ks = 0; ks < 2; ++ks)
        kf[mt * 2 + ks] =
            *(const u16x8*)&Kt[(size_t)(16 * mt + c) * DK + 8 * (4 * ks + qd)];
#pragma unroll
    for (int dt = 0; dt < 4; ++dt)
      vf[dt] = *(const u16x8*)&Vt[(size_t)(16 * dt + c) * LL + 8 * qd];
#pragma unroll
    for (int nt = 0; nt < 2; ++nt)
#pragma unroll
      for (int mt = 0; mt < 2; ++mt)
        bb[nt * 2 + mt] =
            *(const f16x4*)((nt ? BMF1 : BMF0) + (size_t)(it * 2 + mt) * 256);
  };

  auto compute = [&](const u16x8 (&kf)[4], const u16x8 (&vf)[4],
                     const f16x4 (&bb)[4]) {
    // S^T = K.Q^T with bias as accumulator init (C-in add is free)
    f32x4 s[2][2];
    __builtin_amdgcn_s_setprio(1);
#pragma unroll
    for (int mt = 0; mt < 2; ++mt)
#pragma unroll
      for (int nt = 0; nt < 2; ++nt) {
        f16x4 b4 = bb[nt * 2 + mt];
        f32x4 z = {(float)b4[0], (float)b4[1], (float)b4[2], (float)b4[3]};
        z = mfma16(kf[mt * 2 + 0], qf[nt][0], z);
        s[mt][nt] = mfma16(kf[mt * 2 + 1], qf[nt][1], z);
      }
    __builtin_amdgcn_s_setprio(0);
    // p = exp2(s); PV fragments rebuilt in-register per nt:
    // lane holds keys 16mt+4qd+i -> need keys 8qd+e (one swap32+swap16 pair)
    u16x8 pf[2];
#pragma unroll
    for (int nt = 0; nt < 2; ++nt) {
      unsigned L[2], H[2];
#pragma unroll
      for (int mt = 0; mt < 2; ++mt) {
        f32x4 p;
#pragma unroll
        for (int i = 0; i < 4; ++i) p[i] = fexp2(s[mt][nt][i]);
        u32x2 lw = __builtin_bit_cast(u32x2, cvt4(p));
        L[mt] = lw[0];  // keys 16mt+4qd+{0,1}
        H[mt] = lw[1];  // keys 16mt+4qd+{2,3}
      }
      unsigned l0 = L[0], l1 = L[1], h0 = H[0], h1 = H[1];
      swap32(l0, l1); swap16(l0, l1);  // l0 = keys 8qd+{0,1}, l1 = +{4,5}
      swap32(h0, h1); swap16(h0, h1);  // h0 = keys 8qd+{2,3}, h1 = +{6,7}
      u32x4 pw = {l0, h0, l1, h1};
      pf[nt] = __builtin_bit_cast(u16x8, pw);
    }
    // O^T += V^T.P^T ; li += colsum(P^T) via ones-MFMA
    __builtin_amdgcn_s_setprio(1);
#pragma unroll
    for (int nt = 0; nt < 2; ++nt) lacc[nt] = mfma16(ones, pf[nt], lacc[nt]);
#pragma unroll
    for (int dt = 0; dt < 4; ++dt)
#pragma unroll
      for (int nt = 0; nt < 2; ++nt)
        oacc[dt][nt] = mfma16(vf[dt], pf[nt], oacc[dt][nt]);
    __builtin_amdgcn_s_setprio(0);
  };

  loadset(0, kfA, vfA, bA);
#pragma unroll 1
  for (int it = 0; it < 64; it += 2) {
    loadset(it + 1, kfB, vfB, bB);  // in flight during compute(A)
    compute(kfA, vfA, bA);
    if (it + 2 < 64) loadset(it + 2, kfA, vfA, bA);
    compute(kfB, vfB, bB);
  }

  // epilogue: li full per-lane (ones-MFMA), store O[b][q][h*64+d] bf16
#pragma unroll
  for (int nt = 0; nt < 2; ++nt) {
    float rl = 1.f / lacc[nt][0];
    size_t orow = ((size_t)b * LL + q0 + 32 * w + 16 * nt + c) * DM + h * DK;
#pragma unroll
    for (int dt = 0; dt < 4; ++dt)
      *(u16x4*)&O[orow + 16 * dt + 4 * qd] = cvt4(oacc[dt][nt] * rl);
  }
}

// ---------------------------------------------------------------------------
extern "C" void kernel_launch(void* const* d_in, const int* in_sizes, int n_in,
                              void* d_out, int out_size, void* d_ws, size_t ws_size,
                              hipStream_t stream) {
  (void)in_sizes; (void)n_in; (void)ws_size; (void)out_size;
  const float* q = (const float*)d_in[0];
  const float* k = (const float*)d_in[1];
  const float* v = (const float*)d_in[2];
  const int* mask = (const int*)d_in[3];
  const float* bias = (const float*)d_in[4];
  const float* w_qs = (const float*)d_in[5];
  const float* w_ks = (const float*)d_in[6];
  const float* w_vs = (const float*)d_in[7];
  const float* w_fc = (const float*)d_in[8];

  char* ws = (char*)d_ws;
  const size_t MB = 1024 * 1024;
  unsigned short* wT = (unsigned short*)(ws);              // [0,8M)
  f16* bmf = (f16*)(ws + 8 * MB);                          // [8,24M)
  unsigned short* qkvb = (unsigned short*)(ws + 24 * MB);  // [24,48M)
  unsigned short* qh = (unsigned short*)(ws + 48 * MB);    // [48,56M)
  unsigned short* kh = (unsigned short*)(ws + 56 * MB);    // [56,64M)
  unsigned short* vhT = (unsigned short*)(ws + 64 * MB);   // [64,72M)
  unsigned short* Obuf = (unsigned short*)(ws + 72 * MB);  // [72,80M)

  prep_all<<<dim3(18432), dim3(256), 0, stream>>>(w_qs, w_ks, w_vs, w_fc, wT,
                                                  mask, bias, bmf, q, k, v, qkvb);
  proj_gemm<<<dim3(768), 256, 0, stream>>>(qkvb, wT, qh, kh, vhT);
  attn_kern<<<dim3(512), dim3(256), 0, stream>>>(qh, kh, vhT, bmf, Obuf);
  fc_gemm<<<dim3(256), 256, 0, stream>>>(Obuf, wT + (size_t)3 * DM * DM,
                                         (float*)d_out);
}

// Round 7
// 276.323 us; speedup vs baseline: 1.2774x; 1.2774x over previous
//
#include <hip/hip_runtime.h>
#include <cstddef>

#define DEV static __device__ __forceinline__

typedef float f32x4 __attribute__((ext_vector_type(4)));
typedef __bf16 bf16x8 __attribute__((ext_vector_type(8)));
typedef __bf16 bf16x4v __attribute__((ext_vector_type(4)));
typedef unsigned short u16x8 __attribute__((ext_vector_type(8)));
typedef unsigned short u16x4 __attribute__((ext_vector_type(4)));
typedef unsigned u32x2 __attribute__((ext_vector_type(2)));
typedef unsigned u32x4 __attribute__((ext_vector_type(4)));
typedef _Float16 f16;
typedef _Float16 f16x4 __attribute__((ext_vector_type(4)));

constexpr int BB = 2, LL = 2048, DM = 1024, NH = 16, DK = 64;
constexpr float LOG2E = 1.44269504f;

DEV unsigned short f2bf(float f) {
  unsigned u = __builtin_bit_cast(unsigned, f);
  u += 0x7fffu + ((u >> 16) & 1u);  // RNE
  return (unsigned short)(u >> 16);
}
DEV u16x4 cvt4(f32x4 v) {  // packed f32x4 -> bf16x4
  bf16x4v b = __builtin_convertvector(v, bf16x4v);
  return __builtin_bit_cast(u16x4, b);
}
DEV bf16x8 asbf(u16x8 v) { return __builtin_bit_cast(bf16x8, v); }
DEV f32x4 mfma16(u16x8 a, u16x8 b, f32x4 c) {
  return __builtin_amdgcn_mfma_f32_16x16x32_bf16(asbf(a), asbf(b), c, 0, 0, 0);
}
#if __has_builtin(__builtin_amdgcn_exp2f)
DEV float fexp2(float x) { return __builtin_amdgcn_exp2f(x); }
#else
DEV float fexp2(float x) { return exp2f(x); }
#endif
// cross-lane 16/32-row swaps (gfx950): used to rebuild PV fragments in-register
DEV void swap32(unsigned& a, unsigned& b) {
#if __has_builtin(__builtin_amdgcn_permlane32_swap)
  u32x2 r = __builtin_amdgcn_permlane32_swap(a, b, false, false);
  a = r[0]; b = r[1];
#else
  asm("v_permlane32_swap_b32 %0, %1" : "+v"(a), "+v"(b));
#endif
}
DEV void swap16(unsigned& a, unsigned& b) {
#if __has_builtin(__builtin_amdgcn_permlane16_swap)
  u32x2 r = __builtin_amdgcn_permlane16_swap(a, b, false, false);
  a = r[0]; b = r[1];
#else
  asm("v_permlane16_swap_b32 %0, %1" : "+v"(a), "+v"(b));
#endif
}
// async global->LDS, 16B/lane; lds dest wave-uniform base (+lane*16 by HW)
DEV void g2lds16(const void* g, void* l) {
  __builtin_amdgcn_global_load_lds(
      (const __attribute__((address_space(1))) unsigned int*)g,
      (__attribute__((address_space(3))) unsigned int*)l, 16, 0, 0);
}

// ---------------------------------------------------------------------------
// prep_all: ALL preprocessing in one launch.
// Flat grid, block ranges:
//  [0,4096):      prep_w  — transpose+cvt 4 weight mats -> bf16 W^T[N][K]
//  [4096,12288):  prep_bm — bias/mask -> f16 exp2-domain, MFMA-fragment order
//  [12288,18432): prep_cvt — q/k/v fp32 -> bf16
// ---------------------------------------------------------------------------
__global__ __launch_bounds__(256) void prep_all(
    const float* __restrict__ w0, const float* __restrict__ w1,
    const float* __restrict__ w2, const float* __restrict__ w3,
    unsigned short* __restrict__ wT, const int* __restrict__ mask,
    const float* __restrict__ bias, f16* __restrict__ bmf,
    const float* __restrict__ s0, const float* __restrict__ s1,
    const float* __restrict__ s2, unsigned short* __restrict__ qkvb) {
  int f = blockIdx.x, t = threadIdx.x;
  if (f < 4096) {  // ---- prep_w
    __shared__ float tile[32][33];
    int z = f >> 10, rem = f & 1023;
    int k0 = (rem >> 5) * 32, n0 = (rem & 31) * 32;
    const float* W = (z == 0) ? w0 : (z == 1) ? w1 : (z == 2) ? w2 : w3;
    unsigned short* out = wT + (size_t)z * DM * DM;
    int tx = t & 31, ty = t >> 5;
#pragma unroll
    for (int p = 0; p < 4; p++)
      tile[ty + 8 * p][tx] = W[(size_t)(k0 + ty + 8 * p) * DM + n0 + tx];
    __syncthreads();
#pragma unroll
    for (int p = 0; p < 4; p++)
      out[(size_t)(n0 + ty + 8 * p) * DM + k0 + tx] = f2bf(tile[tx][ty + 8 * p]);
  } else if (f < 12288) {  // ---- prep_bm (fragment order)
    int f2 = f - 4096;
    int w = t >> 6, lane = t & 63;
    int bq = f2 >> 5;               // b*128 + qt
    int kt = (f2 & 31) * 4 + w;
    int b = bq >> 7, qt = bq & 127;
    int q = qt * 16 + (lane & 15);
    int k = kt * 16 + (lane >> 4) * 4;
    size_t src = ((size_t)b * LL + q) * LL + k;
    int4 mk = *(const int4*)(mask + src);
    float4 bs = *(const float4*)(bias + src);
    f16x4 o;
    o[0] = (f16)((mk.x == 0 ? -10000.f : bs.x) * LOG2E);
    o[1] = (f16)((mk.y == 0 ? -10000.f : bs.y) * LOG2E);
    o[2] = (f16)((mk.z == 0 ? -10000.f : bs.z) * LOG2E);
    o[3] = (f16)((mk.w == 0 ? -10000.f : bs.w) * LOG2E);
    *(f16x4*)(bmf + ((size_t)bq * 128 + kt) * 256 + lane * 4) = o;
  } else {  // ---- prep_cvt
    int f3 = f - 12288;
    int z = f3 >> 11;
    const float* src = (z == 0) ? s0 : (z == 1) ? s1 : s2;
    size_t i = ((size_t)(f3 & 2047) * 256 + t) * 8;
    float4 a = *(const float4*)(src + i);
    float4 b = *(const float4*)(src + i + 4);
    u16x8 o;
    o[0] = f2bf(a.x); o[1] = f2bf(a.y); o[2] = f2bf(a.z); o[3] = f2bf(a.w);
    o[4] = f2bf(b.x); o[5] = f2bf(b.y); o[6] = f2bf(b.z); o[7] = f2bf(b.w);
    *(u16x8*)(qkvb + (size_t)z * (size_t)(BB * LL) * DM + i) = o;
  }
}

// ---------------------------------------------------------------------------
// GEMM core, m97 structure: 128x128 tile, BK=64, single-buffered 32 KB LDS,
// global_load_lds staging, 2 barriers/iter. Swizzle on the GLOBAL address
// side (gsw); LDS dest is linear base+lane*16. (proj: 3 blk/CU resident ->
// cross-block TLP hides the barrier drain; keep single-buffer.)
// ---------------------------------------------------------------------------
template <int KITERS>
DEV void gemm_core(const unsigned short* __restrict__ A,
                   const unsigned short* __restrict__ BT,
                   unsigned short* Al, unsigned short* Bl,
                   int m0, int n0, int k0beg, int t, f32x4 (&acc)[4][4]) {
  int lane = t & 63, c = lane & 15, qd = lane >> 4;
  int w = t >> 6, wm = w >> 1, wn = w & 1;
  int r0 = t >> 3;               // 0..31; rows r0+32p keep same low 3 bits
  int gsw = (t & 7) ^ (r0 & 7);  // swizzled col-group for this thread

#pragma unroll 1
  for (int kk = 0; kk < KITERS; ++kk) {
    int k0 = k0beg + kk * 64;
#pragma unroll
    for (int p = 0; p < 4; ++p) {  // DMA: wave-uniform LDS base + lane*16
      g2lds16(&A[(size_t)(m0 + 32 * p + r0) * DM + k0 + 8 * gsw],
              &Al[p * 2048 + w * 512]);
      g2lds16(&BT[(size_t)(n0 + 32 * p + r0) * DM + k0 + 8 * gsw],
              &Bl[p * 2048 + w * 512]);
    }
    __syncthreads();  // drain DMA (vmcnt(0) folded into barrier)
#pragma unroll
    for (int ks = 0; ks < 2; ++ks) {
      u16x8 af[4], bfr[4];
#pragma unroll
      for (int mt = 0; mt < 4; ++mt)
        af[mt] = *(const u16x8*)&Al[(64 * wm + 16 * mt + c) * 64 +
                                    (((4 * ks + qd) ^ (c & 7)) << 3)];
#pragma unroll
      for (int nt = 0; nt < 4; ++nt)
        bfr[nt] = *(const u16x8*)&Bl[(64 * wn + 16 * nt + c) * 64 +
                                     (((4 * ks + qd) ^ (c & 7)) << 3)];
#pragma unroll
      for (int mt = 0; mt < 4; ++mt)
#pragma unroll
        for (int nt = 0; nt < 4; ++nt)
          acc[mt][nt] = mfma16(af[mt], bfr[nt], acc[mt][nt]);
    }
    __syncthreads();  // all reads done before next stage overwrites
  }
}

// fused q/k/v projections: 1-D grid 768, XCD-chunked swizzle (768%8==0).
__global__ __launch_bounds__(256, 3) void proj_gemm(
    const unsigned short* __restrict__ qkvb, const unsigned short* __restrict__ wT,
    unsigned short* __restrict__ qh, unsigned short* __restrict__ kh,
    unsigned short* __restrict__ vT) {
  __shared__ unsigned short Al[128 * 64];  // 16 KiB
  __shared__ unsigned short Bl[128 * 64];  // 16 KiB
  int o = blockIdx.x;
  int wg = (o & 7) * 96 + (o >> 3);  // bijective: 96 consecutive wgs per XCD
  int z = wg >> 8, rem = wg & 255;
  int m0 = (rem >> 3) * 128, n0 = (rem & 7) * 128;
  const unsigned short* A = qkvb + (size_t)z * BB * LL * DM;
  const unsigned short* BT = wT + (size_t)z * DM * DM;
  int t = threadIdx.x, lane = t & 63, c = lane & 15, qd = lane >> 4;
  int w = t >> 6, wm = w >> 1, wn = w & 1;
  f32x4 acc[4][4] = {};
  gemm_core<DM / 64>(A, BT, Al, Bl, m0, n0, 0, t, acc);

  if (z == 2) {  // V: per-head transposed vT[b][h][d][l]
#pragma unroll
    for (int mt = 0; mt < 4; ++mt)
#pragma unroll
      for (int nt = 0; nt < 4; ++nt) {
        int n = n0 + 64 * wn + 16 * nt + c;
        int h = n >> 6, d = n & 63;
        int m = m0 + 64 * wm + 16 * mt + 4 * qd;  // i=0..3 consecutive in l
        int b = m >> 11, l = m & 2047;
        *(u16x4*)&vT[(((size_t)b * NH + h) * DK + d) * LL + l] = cvt4(acc[mt][nt]);
      }
  } else {  // Q/K: head-split [b][h][l][d]; Q carries temperature*log2e
    unsigned short* Ch = z ? kh : qh;
    float scale = z ? 1.0f : 0.125f * LOG2E;
#pragma unroll
    for (int mt = 0; mt < 4; ++mt)
#pragma unroll
      for (int nt = 0; nt < 4; ++nt) {
        int n = n0 + 64 * wn + 16 * nt + c;
        int h = n >> 6, d = n & 63;
#pragma unroll
        for (int i = 0; i < 4; ++i) {
          int m = m0 + 64 * wm + 16 * mt + 4 * qd + i;
          int b = m >> 11, l = m & 2047;
          Ch[(((size_t)b * NH + h) * LL + l) * DK + d] = f2bf(acc[mt][nt][i] * scale);
        }
      }
  }
}

// final fc: single-K (16 iters), DOUBLE-BUFFERED LDS (one barrier/iter) —
// at 1 block/CU there is no cross-block TLP to hide the DMA drain, so the
// prefetch must overlap compute within the block. Direct f32 stores.
// 1-D grid 256, XCD-chunked swizzle (256%8==0).
__global__ __launch_bounds__(256, 2) void fc_gemm(const unsigned short* __restrict__ A,
                                                  const unsigned short* __restrict__ BT,
                                                  float* __restrict__ C) {
  __shared__ unsigned short Al[2][128 * 64];  // 32 KiB
  __shared__ unsigned short Bl[2][128 * 64];  // 32 KiB
  int o = blockIdx.x;
  int wg = (o & 7) * 32 + (o >> 3);  // 32 consecutive wgs per XCD
  int m0 = (wg >> 3) * 128, n0 = (wg & 7) * 128;
  int t = threadIdx.x, lane = t & 63, c = lane & 15, qd = lane >> 4;
  int w = t >> 6, wm = w >> 1, wn = w & 1;
  int r0 = t >> 3, gsw = (t & 7) ^ (r0 & 7);
  f32x4 acc[4][4] = {};

  auto stage = [&](int kk, int buf) {
    int k0 = kk * 64;
#pragma unroll
    for (int p = 0; p < 4; ++p) {
      g2lds16(&A[(size_t)(m0 + 32 * p + r0) * DM + k0 + 8 * gsw],
              &Al[buf][p * 2048 + w * 512]);
      g2lds16(&BT[(size_t)(n0 + 32 * p + r0) * DM + k0 + 8 * gsw],
              &Bl[buf][p * 2048 + w * 512]);
    }
  };
  auto compute = [&](int buf) {
#pragma unroll
    for (int ks = 0; ks < 2; ++ks) {
      u16x8 af[4], bfr[4];
#pragma unroll
      for (int mt = 0; mt < 4; ++mt)
        af[mt] = *(const u16x8*)&Al[buf][(64 * wm + 16 * mt + c) * 64 +
                                         (((4 * ks + qd) ^ (c & 7)) << 3)];
#pragma unroll
      for (int nt = 0; nt < 4; ++nt)
        bfr[nt] = *(const u16x8*)&Bl[buf][(64 * wn + 16 * nt + c) * 64 +
                                          (((4 * ks + qd) ^ (c & 7)) << 3)];
#pragma unroll
      for (int mt = 0; mt < 4; ++mt)
#pragma unroll
        for (int nt = 0; nt < 4; ++nt)
          acc[mt][nt] = mfma16(af[mt], bfr[nt], acc[mt][nt]);
    }
  };

  stage(0, 0);
  __syncthreads();
#pragma unroll 1
  for (int kk = 0; kk < 16; ++kk) {
    if (kk + 1 < 16) stage(kk + 1, (kk + 1) & 1);  // DMA flies during compute
    compute(kk & 1);
    __syncthreads();  // drains prefetch DMA + read completion
  }

#pragma unroll
  for (int mt = 0; mt < 4; ++mt)
#pragma unroll
    for (int nt = 0; nt < 4; ++nt) {
      int n = n0 + 64 * wn + 16 * nt + c;
#pragma unroll
      for (int i = 0; i < 4; ++i) {
        int m = m0 + 64 * wm + 16 * mt + 4 * qd + i;
        C[(size_t)m * DM + n] = acc[mt][nt][i];
      }
    }
}

// ---------------------------------------------------------------------------
// attn: round-4 structure (measured 62.8 us) + XCD-chunked block swizzle.
// 64 q-rows/block (4 waves x 16 q), TK=64, ping-pong K/V DMA staging,
// grid 1024 = 4 blocks/CU = 16 waves/CU, LDS 32 KB. Swizzle: 128 consecutive
// wgs per XCD = 4 heads x 32 q-blocks -> 2 MB K/V per XCD fits 4 MB L2
// (round 5 measured FETCH 78->45 MB); L2-hit DMA also shortens the per-iter
// barrier drain (~200 vs ~900 cyc).
//  - bias folds into QK^T accumulator init (free C-in add).
//  - P^T never touches LDS (cvt4 + permlane32/16_swap rebuilds PV frags).
//  - li via ones-row MFMA; s_setprio(1) around MFMA clusters.
// ---------------------------------------------------------------------------
__global__ __launch_bounds__(256, 4) void attn_kern(
    const unsigned short* __restrict__ qh, const unsigned short* __restrict__ kh,
    const unsigned short* __restrict__ vT, const f16* __restrict__ bmf,
    unsigned short* __restrict__ O) {
  __shared__ unsigned short Kb[2][4096];  // 16 KiB swizzled [key][d]
  __shared__ unsigned short Vb[2][4096];  // 16 KiB swizzled [d][key]

  int t = threadIdx.x, w = t >> 6, lane = t & 63, c = lane & 15, qd = lane >> 4;
  int o = blockIdx.x;
  int wg = (o & 7) * 128 + (o >> 3);  // bijective XCD chunking (1024%8==0)
  int x = wg & 31, h = (wg >> 5) & 15, b = wg >> 9;
  int q0 = x * 64;
  const unsigned short* Q = qh + (((size_t)b * NH + h) * LL + q0) * DK;
  const unsigned short* K = kh + ((size_t)b * NH + h) * LL * DK;
  const unsigned short* V = vT + ((size_t)b * NH + h) * DK * LL;
  // fragment-ordered bias: tile (qt, kt), 256 f16 per tile, lane-major
  const f16* BMF = bmf + (((size_t)b * 128 + x * 4 + w) * 128) * 256 + lane * 4;
  int rt = t >> 3, gg = t & 7;

  // stage Q (64x64) into Kb[1]; K/V tile 0 into Kb[0]/Vb[0]
#pragma unroll
  for (int r = 0; r < 2; ++r) {
    int row = r * 32 + rt;
    int sc = ((gg ^ (row & 7)) << 3);
    g2lds16(&Q[(size_t)row * DK + sc], &Kb[1][r * 2048 + w * 512]);
    g2lds16(&K[(size_t)row * DK + sc], &Kb[0][r * 2048 + w * 512]);
    g2lds16(&V[(size_t)row * LL + sc], &Vb[0][r * 2048 + w * 512]);
  }
  f16x4 bA[4], bB[4];  // ping-pong bias registers, [mt]
#pragma unroll
  for (int mt = 0; mt < 4; ++mt) bA[mt] = *(const f16x4*)&BMF[(size_t)mt * 256];
  __syncthreads();  // drains Q/K/V DMA

  u16x8 qf[2];  // [ks]; wave w owns q rows 16w..16w+15
#pragma unroll
  for (int ks = 0; ks < 2; ++ks)
    qf[ks] = *(const u16x8*)&Kb[1][(16 * w + c) * 64 +
                                   (((4 * ks + qd) ^ (c & 7)) << 3)];
  __syncthreads();  // qf in regs before tile-1 prefetch overwrites Kb[1]

  const u16x8 ones = {0x3F80, 0x3F80, 0x3F80, 0x3F80,
                      0x3F80, 0x3F80, 0x3F80, 0x3F80};  // bf16 1.0
  f32x4 lacc = {};     // li accumulator via ones-MFMA (all rows identical)
  f32x4 oacc[4] = {};  // [dt]

  auto body = [&](int it, f16x4 (&bc)[4], f16x4 (&bn)[4]) {
    int cur = it & 1;
    const unsigned short* Kl = Kb[cur];
    const unsigned short* Vt = Vb[cur];
    if (it + 1 < 32) {  // prefetch next K/V tiles (LDS) + next bias (regs)
      int nb = cur ^ 1, kt1 = (it + 1) * 64;
#pragma unroll
      for (int r = 0; r < 2; ++r) {
        int row = r * 32 + rt;
        int sc = ((gg ^ (row & 7)) << 3);
        g2lds16(&K[(size_t)(kt1 + row) * DK + sc], &Kb[nb][r * 2048 + w * 512]);
        g2lds16(&V[(size_t)row * LL + kt1 + sc], &Vb[nb][r * 2048 + w * 512]);
      }
#pragma unroll
      for (int mt = 0; mt < 4; ++mt)
        bn[mt] = *(const f16x4*)&BMF[(size_t)((it + 1) * 4 + mt) * 256];
    }

    // S^T = K.Q^T with bias as accumulator init (C-in add is free)
    f32x4 s[4];
    __builtin_amdgcn_s_setprio(1);
#pragma unroll
    for (int mt = 0; mt < 4; ++mt) {
      int row = 16 * mt + c;
      u16x8 k0f = *(const u16x8*)&Kl[row * 64 + ((qd ^ (c & 7)) << 3)];
      u16x8 k1f = *(const u16x8*)&Kl[row * 64 + (((4 + qd) ^ (c & 7)) << 3)];
      f16x4 b4 = bc[mt];
      f32x4 z = {(float)b4[0], (float)b4[1], (float)b4[2], (float)b4[3]};
      z = mfma16(k0f, qf[0], z);
      s[mt] = mfma16(k1f, qf[1], z);
    }
    __builtin_amdgcn_s_setprio(0);
    // p = exp2(s); PV fragments rebuilt in-register:
    // one permlane32_swap + one permlane16_swap per word pair.
    u16x8 pf[2];
    {
      unsigned L[4], H[4];
#pragma unroll
      for (int mt = 0; mt < 4; ++mt) {
        f32x4 p;
#pragma unroll
        for (int i = 0; i < 4; ++i) p[i] = fexp2(s[mt][i]);
        u32x2 lw = __builtin_bit_cast(u32x2, cvt4(p));
        L[mt] = lw[0];  // keys 16mt+4qd+{0,1}
        H[mt] = lw[1];  // keys 16mt+4qd+{2,3}
      }
#pragma unroll
      for (int ks = 0; ks < 2; ++ks) {
        unsigned l0 = L[2 * ks], l1 = L[2 * ks + 1];
        unsigned h0 = H[2 * ks], h1 = H[2 * ks + 1];
        swap32(l0, l1); swap16(l0, l1);  // l0 = keys 8qd+{0,1}, l1 = +{4,5}
        swap32(h0, h1); swap16(h0, h1);  // h0 = keys 8qd+{2,3}, h1 = +{6,7}
        u32x4 pw = {l0, h0, l1, h1};
        pf[ks] = __builtin_bit_cast(u16x8, pw);
      }
    }
    // O^T += V^T.P^T ; li += colsum(P^T) via ones-MFMA
    __builtin_amdgcn_s_setprio(1);
    lacc = mfma16(ones, pf[0], lacc);
    lacc = mfma16(ones, pf[1], lacc);
#pragma unroll
    for (int dt = 0; dt < 4; ++dt) {
      int row = 16 * dt + c;
      u16x8 v0f = *(const u16x8*)&Vt[row * 64 + ((qd ^ (c & 7)) << 3)];
      u16x8 v1f = *(const u16x8*)&Vt[row * 64 + (((4 + qd) ^ (c & 7)) << 3)];
      oacc[dt] = mfma16(v0f, pf[0], oacc[dt]);
      oacc[dt] = mfma16(v1f, pf[1], oacc[dt]);
    }
    __builtin_amdgcn_s_setprio(0);
    __syncthreads();  // drains prefetch DMA (in flight during compute)
  };

#pragma unroll 1
  for (int it = 0; it < 32; it += 2) {
    body(it, bA, bB);
    body(it + 1, bB, bA);
  }

  // epilogue: li already full per-lane (ones-MFMA), store O[b][q][h*64+d]
  {
    float rl = 1.f / lacc[0];
    size_t orow = ((size_t)b * LL + q0 + 16 * w + c) * DM + h * DK;
#pragma unroll
    for (int dt = 0; dt < 4; ++dt)
      *(u16x4*)&O[orow + 16 * dt + 4 * qd] = cvt4(oacc[dt] * rl);
  }
}

// ---------------------------------------------------------------------------
extern "C" void kernel_launch(void* const* d_in, const int* in_sizes, int n_in,
                              void* d_out, int out_size, void* d_ws, size_t ws_size,
                              hipStream_t stream) {
  (void)in_sizes; (void)n_in; (void)ws_size; (void)out_size;
  const float* q = (const float*)d_in[0];
  const float* k = (const float*)d_in[1];
  const float* v = (const float*)d_in[2];
  const int* mask = (const int*)d_in[3];
  const float* bias = (const float*)d_in[4];
  const float* w_qs = (const float*)d_in[5];
  const float* w_ks = (const float*)d_in[6];
  const float* w_vs = (const float*)d_in[7];
  const float* w_fc = (const float*)d_in[8];

  char* ws = (char*)d_ws;
  const size_t MB = 1024 * 1024;
  unsigned short* wT = (unsigned short*)(ws);              // [0,8M)
  f16* bmf = (f16*)(ws + 8 * MB);                          // [8,24M)
  unsigned short* qkvb = (unsigned short*)(ws + 24 * MB);  // [24,48M)
  unsigned short* qh = (unsigned short*)(ws + 48 * MB);    // [48,56M)
  unsigned short* kh = (unsigned short*)(ws + 56 * MB);    // [56,64M)
  unsigned short* vhT = (unsigned short*)(ws + 64 * MB);   // [64,72M)
  unsigned short* Obuf = (unsigned short*)(ws + 72 * MB);  // [72,80M)

  prep_all<<<dim3(18432), dim3(256), 0, stream>>>(w_qs, w_ks, w_vs, w_fc, wT,
                                                  mask, bias, bmf, q, k, v, qkvb);
  proj_gemm<<<dim3(768), 256, 0, stream>>>(qkvb, wT, qh, kh, vhT);
  attn_kern<<<dim3(1024), dim3(256), 0, stream>>>(qh, kh, vhT, bmf, Obuf);
  fc_gemm<<<dim3(256), 256, 0, stream>>>(Obuf, wT + (size_t)3 * DM * DM,
                                         (float*)d_out);
}

// Round 8
// 267.139 us; speedup vs baseline: 1.3213x; 1.0344x over previous
//
#include <hip/hip_runtime.h>
#include <cstddef>

#define DEV static __device__ __forceinline__

typedef float f32x4 __attribute__((ext_vector_type(4)));
typedef __bf16 bf16x8 __attribute__((ext_vector_type(8)));
typedef __bf16 bf16x4v __attribute__((ext_vector_type(4)));
typedef unsigned short u16x8 __attribute__((ext_vector_type(8)));
typedef unsigned short u16x4 __attribute__((ext_vector_type(4)));
typedef unsigned u32x2 __attribute__((ext_vector_type(2)));
typedef unsigned u32x4 __attribute__((ext_vector_type(4)));
typedef _Float16 f16;
typedef _Float16 f16x4 __attribute__((ext_vector_type(4)));

constexpr int BB = 2, LL = 2048, DM = 1024, NH = 16, DK = 64;
constexpr float LOG2E = 1.44269504f;

DEV unsigned short f2bf(float f) {
  unsigned u = __builtin_bit_cast(unsigned, f);
  u += 0x7fffu + ((u >> 16) & 1u);  // RNE
  return (unsigned short)(u >> 16);
}
DEV u16x4 cvt4(f32x4 v) {  // packed f32x4 -> bf16x4
  bf16x4v b = __builtin_convertvector(v, bf16x4v);
  return __builtin_bit_cast(u16x4, b);
}
DEV bf16x8 asbf(u16x8 v) { return __builtin_bit_cast(bf16x8, v); }
DEV f32x4 mfma16(u16x8 a, u16x8 b, f32x4 c) {
  return __builtin_amdgcn_mfma_f32_16x16x32_bf16(asbf(a), asbf(b), c, 0, 0, 0);
}
#if __has_builtin(__builtin_amdgcn_exp2f)
DEV float fexp2(float x) { return __builtin_amdgcn_exp2f(x); }
#else
DEV float fexp2(float x) { return exp2f(x); }
#endif
// cross-lane 16/32-row swaps (gfx950): used to rebuild PV fragments in-register
DEV void swap32(unsigned& a, unsigned& b) {
#if __has_builtin(__builtin_amdgcn_permlane32_swap)
  u32x2 r = __builtin_amdgcn_permlane32_swap(a, b, false, false);
  a = r[0]; b = r[1];
#else
  asm("v_permlane32_swap_b32 %0, %1" : "+v"(a), "+v"(b));
#endif
}
DEV void swap16(unsigned& a, unsigned& b) {
#if __has_builtin(__builtin_amdgcn_permlane16_swap)
  u32x2 r = __builtin_amdgcn_permlane16_swap(a, b, false, false);
  a = r[0]; b = r[1];
#else
  asm("v_permlane16_swap_b32 %0, %1" : "+v"(a), "+v"(b));
#endif
}
// async global->LDS, 16B/lane; lds dest wave-uniform base (+lane*16 by HW)
DEV void g2lds16(const void* g, void* l) {
  __builtin_amdgcn_global_load_lds(
      (const __attribute__((address_space(1))) unsigned int*)g,
      (__attribute__((address_space(3))) unsigned int*)l, 16, 0, 0);
}

// ---------------------------------------------------------------------------
// prep_all: ALL preprocessing in one launch.
// Flat grid, block ranges:
//  [0,4096):      prep_w  — transpose+cvt 4 weight mats -> bf16 W^T[N][K]
//  [4096,12288):  prep_bm — bias/mask -> f16 exp2-domain, MFMA-fragment order
//  [12288,18432): prep_cvt — q/k/v fp32 -> bf16
// ---------------------------------------------------------------------------
__global__ __launch_bounds__(256) void prep_all(
    const float* __restrict__ w0, const float* __restrict__ w1,
    const float* __restrict__ w2, const float* __restrict__ w3,
    unsigned short* __restrict__ wT, const int* __restrict__ mask,
    const float* __restrict__ bias, f16* __restrict__ bmf,
    const float* __restrict__ s0, const float* __restrict__ s1,
    const float* __restrict__ s2, unsigned short* __restrict__ qkvb) {
  int f = blockIdx.x, t = threadIdx.x;
  if (f < 4096) {  // ---- prep_w
    __shared__ float tile[32][33];
    int z = f >> 10, rem = f & 1023;
    int k0 = (rem >> 5) * 32, n0 = (rem & 31) * 32;
    const float* W = (z == 0) ? w0 : (z == 1) ? w1 : (z == 2) ? w2 : w3;
    unsigned short* out = wT + (size_t)z * DM * DM;
    int tx = t & 31, ty = t >> 5;
#pragma unroll
    for (int p = 0; p < 4; p++)
      tile[ty + 8 * p][tx] = W[(size_t)(k0 + ty + 8 * p) * DM + n0 + tx];
    __syncthreads();
#pragma unroll
    for (int p = 0; p < 4; p++)
      out[(size_t)(n0 + ty + 8 * p) * DM + k0 + tx] = f2bf(tile[tx][ty + 8 * p]);
  } else if (f < 12288) {  // ---- prep_bm (fragment order)
    int f2 = f - 4096;
    int w = t >> 6, lane = t & 63;
    int bq = f2 >> 5;               // b*128 + qt
    int kt = (f2 & 31) * 4 + w;
    int b = bq >> 7, qt = bq & 127;
    int q = qt * 16 + (lane & 15);
    int k = kt * 16 + (lane >> 4) * 4;
    size_t src = ((size_t)b * LL + q) * LL + k;
    int4 mk = *(const int4*)(mask + src);
    float4 bs = *(const float4*)(bias + src);
    f16x4 o;
    o[0] = (f16)((mk.x == 0 ? -10000.f : bs.x) * LOG2E);
    o[1] = (f16)((mk.y == 0 ? -10000.f : bs.y) * LOG2E);
    o[2] = (f16)((mk.z == 0 ? -10000.f : bs.z) * LOG2E);
    o[3] = (f16)((mk.w == 0 ? -10000.f : bs.w) * LOG2E);
    *(f16x4*)(bmf + ((size_t)bq * 128 + kt) * 256 + lane * 4) = o;
  } else {  // ---- prep_cvt
    int f3 = f - 12288;
    int z = f3 >> 11;
    const float* src = (z == 0) ? s0 : (z == 1) ? s1 : s2;
    size_t i = ((size_t)(f3 & 2047) * 256 + t) * 8;
    float4 a = *(const float4*)(src + i);
    float4 b = *(const float4*)(src + i + 4);
    u16x8 o;
    o[0] = f2bf(a.x); o[1] = f2bf(a.y); o[2] = f2bf(a.z); o[3] = f2bf(a.w);
    o[4] = f2bf(b.x); o[5] = f2bf(b.y); o[6] = f2bf(b.z); o[7] = f2bf(b.w);
    *(u16x8*)(qkvb + (size_t)z * (size_t)(BB * LL) * DM + i) = o;
  }
}

// ---------------------------------------------------------------------------
// GEMM core, m97 structure: 128x128 tile, BK=64, single-buffered 32 KB LDS,
// global_load_lds staging, 2 barriers/iter. Swizzle on the GLOBAL address
// side (gsw); LDS dest is linear base+lane*16.
// ---------------------------------------------------------------------------
template <int KITERS>
DEV void gemm_core(const unsigned short* __restrict__ A,
                   const unsigned short* __restrict__ BT,
                   unsigned short* Al, unsigned short* Bl,
                   int m0, int n0, int k0beg, int t, f32x4 (&acc)[4][4]) {
  int lane = t & 63, c = lane & 15, qd = lane >> 4;
  int w = t >> 6, wm = w >> 1, wn = w & 1;
  int r0 = t >> 3;               // 0..31; rows r0+32p keep same low 3 bits
  int gsw = (t & 7) ^ (r0 & 7);  // swizzled col-group for this thread

#pragma unroll 1
  for (int kk = 0; kk < KITERS; ++kk) {
    int k0 = k0beg + kk * 64;
#pragma unroll
    for (int p = 0; p < 4; ++p) {  // DMA: wave-uniform LDS base + lane*16
      g2lds16(&A[(size_t)(m0 + 32 * p + r0) * DM + k0 + 8 * gsw],
              &Al[p * 2048 + w * 512]);
      g2lds16(&BT[(size_t)(n0 + 32 * p + r0) * DM + k0 + 8 * gsw],
              &Bl[p * 2048 + w * 512]);
    }
    __syncthreads();  // drain DMA (vmcnt(0) folded into barrier)
#pragma unroll
    for (int ks = 0; ks < 2; ++ks) {
      u16x8 af[4], bfr[4];
#pragma unroll
      for (int mt = 0; mt < 4; ++mt)
        af[mt] = *(const u16x8*)&Al[(64 * wm + 16 * mt + c) * 64 +
                                    (((4 * ks + qd) ^ (c & 7)) << 3)];
#pragma unroll
      for (int nt = 0; nt < 4; ++nt)
        bfr[nt] = *(const u16x8*)&Bl[(64 * wn + 16 * nt + c) * 64 +
                                     (((4 * ks + qd) ^ (c & 7)) << 3)];
#pragma unroll
      for (int mt = 0; mt < 4; ++mt)
#pragma unroll
        for (int nt = 0; nt < 4; ++nt)
          acc[mt][nt] = mfma16(af[mt], bfr[nt], acc[mt][nt]);
    }
    __syncthreads();  // all reads done before next stage overwrites
  }
}

// fused q/k/v projections: 1-D grid 768, XCD-chunked swizzle (768%8==0).
__global__ __launch_bounds__(256, 3) void proj_gemm(
    const unsigned short* __restrict__ qkvb, const unsigned short* __restrict__ wT,
    unsigned short* __restrict__ qh, unsigned short* __restrict__ kh,
    unsigned short* __restrict__ vT) {
  __shared__ unsigned short Al[128 * 64];  // 16 KiB
  __shared__ unsigned short Bl[128 * 64];  // 16 KiB
  int o = blockIdx.x;
  int wg = (o & 7) * 96 + (o >> 3);  // bijective: 96 consecutive wgs per XCD
  int z = wg >> 8, rem = wg & 255;
  int m0 = (rem >> 3) * 128, n0 = (rem & 7) * 128;
  const unsigned short* A = qkvb + (size_t)z * BB * LL * DM;
  const unsigned short* BT = wT + (size_t)z * DM * DM;
  int t = threadIdx.x, lane = t & 63, c = lane & 15, qd = lane >> 4;
  int w = t >> 6, wm = w >> 1, wn = w & 1;
  f32x4 acc[4][4] = {};
  gemm_core<DM / 64>(A, BT, Al, Bl, m0, n0, 0, t, acc);

  if (z == 2) {  // V: per-head transposed vT[b][h][d][l]
#pragma unroll
    for (int mt = 0; mt < 4; ++mt)
#pragma unroll
      for (int nt = 0; nt < 4; ++nt) {
        int n = n0 + 64 * wn + 16 * nt + c;
        int h = n >> 6, d = n & 63;
        int m = m0 + 64 * wm + 16 * mt + 4 * qd;  // i=0..3 consecutive in l
        int b = m >> 11, l = m & 2047;
        *(u16x4*)&vT[(((size_t)b * NH + h) * DK + d) * LL + l] = cvt4(acc[mt][nt]);
      }
  } else {  // Q/K: head-split [b][h][l][d]; Q carries temperature*log2e
    unsigned short* Ch = z ? kh : qh;
    float scale = z ? 1.0f : 0.125f * LOG2E;
#pragma unroll
    for (int mt = 0; mt < 4; ++mt)
#pragma unroll
      for (int nt = 0; nt < 4; ++nt) {
        int n = n0 + 64 * wn + 16 * nt + c;
        int h = n >> 6, d = n & 63;
#pragma unroll
        for (int i = 0; i < 4; ++i) {
          int m = m0 + 64 * wm + 16 * mt + 4 * qd + i;
          int b = m >> 11, l = m & 2047;
          Ch[(((size_t)b * NH + h) * LL + l) * DK + d] = f2bf(acc[mt][nt][i] * scale);
        }
      }
  }
}

// final fc: single-K (16 iters), direct f32 stores (round-4 form — the
// double-buffer variant regressed ~9 us). 1-D grid 256, XCD swizzle.
__global__ __launch_bounds__(256, 3) void fc_gemm(const unsigned short* __restrict__ A,
                                                  const unsigned short* __restrict__ BT,
                                                  float* __restrict__ C) {
  __shared__ unsigned short Al[128 * 64];
  __shared__ unsigned short Bl[128 * 64];
  int o = blockIdx.x;
  int wg = (o & 7) * 32 + (o >> 3);  // 32 consecutive wgs per XCD
  int m0 = (wg >> 3) * 128, n0 = (wg & 7) * 128;
  int t = threadIdx.x, lane = t & 63, c = lane & 15, qd = lane >> 4;
  int w = t >> 6, wm = w >> 1, wn = w & 1;
  f32x4 acc[4][4] = {};
  gemm_core<DM / 64>(A, BT, Al, Bl, m0, n0, 0, t, acc);
#pragma unroll
  for (int mt = 0; mt < 4; ++mt)
#pragma unroll
    for (int nt = 0; nt < 4; ++nt) {
      int n = n0 + 64 * wn + 16 * nt + c;
#pragma unroll
      for (int i = 0; i < 4; ++i) {
        int m = m0 + 64 * wm + 16 * mt + 4 * qd + i;
        C[(size_t)m * DM + n] = acc[mt][nt][i];
      }
    }
}

// ---------------------------------------------------------------------------
// attn: SOFTWARE-PIPELINED flash loop. Window j computes softmax(j-1) and
// QK(j) — independent work (VALU vs LDS+MFMA) the scheduler can interleave —
// then PV(j-1). s carried in regs across the barrier; V triple-buffered so
// V(j-1) survives into window j while DMA(j+1) lands elsewhere.
// 64 q-rows/block (4 waves x 16 q), TK=64, grid 1024 = 4 blk/CU (XCD swizzle),
// LDS 40 KB (Kb 2x8 + Vb 3x8) -> 4 blocks/CU exactly fills 160 KB.
//  - bias folds into QK^T accumulator init (free C-in add).
//  - P^T never touches LDS (cvt4 + permlane32/16_swap rebuilds PV frags).
//  - li via ones-row MFMA; setprio(1) wraps the whole compute region (no
//    internal fence so SM/QK interleave freely).
// ---------------------------------------------------------------------------
__global__ __launch_bounds__(256, 4) void attn_kern(
    const unsigned short* __restrict__ qh, const unsigned short* __restrict__ kh,
    const unsigned short* __restrict__ vT, const f16* __restrict__ bmf,
    unsigned short* __restrict__ O) {
  __shared__ unsigned short Kb[2][4096];  // 16 KiB swizzled [key][d]
  __shared__ unsigned short Vb[3][4096];  // 24 KiB swizzled [d][key], 3-deep

  int t = threadIdx.x, w = t >> 6, lane = t & 63, c = lane & 15, qd = lane >> 4;
  int o = blockIdx.x;
  int wg = (o & 7) * 128 + (o >> 3);  // bijective XCD chunking (1024%8==0)
  int x = wg & 31, h = (wg >> 5) & 15, b = wg >> 9;
  int q0 = x * 64;
  const unsigned short* Q = qh + (((size_t)b * NH + h) * LL + q0) * DK;
  const unsigned short* K = kh + ((size_t)b * NH + h) * LL * DK;
  const unsigned short* V = vT + ((size_t)b * NH + h) * DK * LL;
  const f16* BMF = bmf + (((size_t)b * 128 + x * 4 + w) * 128) * 256 + lane * 4;
  int rt = t >> 3, gg = t & 7;

  // ---- prologue: Q->Kb[1], K0->Kb[0], V0->Vb[0]; bias(0)->bc
  f16x4 bc[4], bn[4];
#pragma unroll
  for (int r = 0; r < 2; ++r) {
    int row = r * 32 + rt;
    int sc = ((gg ^ (row & 7)) << 3);
    g2lds16(&Q[(size_t)row * DK + sc], &Kb[1][r * 2048 + w * 512]);
    g2lds16(&K[(size_t)row * DK + sc], &Kb[0][r * 2048 + w * 512]);
    g2lds16(&V[(size_t)row * LL + sc], &Vb[0][r * 2048 + w * 512]);
  }
#pragma unroll
  for (int mt = 0; mt < 4; ++mt) bc[mt] = *(const f16x4*)&BMF[(size_t)mt * 256];
  __syncthreads();  // drains Q/K/V DMA

  u16x8 qf[2];  // wave w owns q rows 16w..16w+15
#pragma unroll
  for (int ks = 0; ks < 2; ++ks)
    qf[ks] = *(const u16x8*)&Kb[1][(16 * w + c) * 64 +
                                   (((4 * ks + qd) ^ (c & 7)) << 3)];
  __syncthreads();  // qf in regs before tile-1 DMA overwrites Kb[1]

  // ---- window 0: DMA tile 1; QK(0) with bias(0) C-init -> sP
  {
#pragma unroll
    for (int r = 0; r < 2; ++r) {
      int row = r * 32 + rt;
      int sc = ((gg ^ (row & 7)) << 3);
      g2lds16(&K[(size_t)(64 + row) * DK + sc], &Kb[1][r * 2048 + w * 512]);
      g2lds16(&V[(size_t)row * LL + 64 + sc], &Vb[1][r * 2048 + w * 512]);
    }
#pragma unroll
    for (int mt = 0; mt < 4; ++mt)
      bn[mt] = *(const f16x4*)&BMF[(size_t)(4 + mt) * 256];
  }
  f32x4 sP[4];
  __builtin_amdgcn_s_setprio(1);
#pragma unroll
  for (int mt = 0; mt < 4; ++mt) {
    int row = 16 * mt + c;
    u16x8 k0f = *(const u16x8*)&Kb[0][row * 64 + ((qd ^ (c & 7)) << 3)];
    u16x8 k1f = *(const u16x8*)&Kb[0][row * 64 + (((4 + qd) ^ (c & 7)) << 3)];
    f16x4 b4 = bc[mt];
    f32x4 z = {(float)b4[0], (float)b4[1], (float)b4[2], (float)b4[3]};
    z = mfma16(k0f, qf[0], z);
    sP[mt] = mfma16(k1f, qf[1], z);
  }
  __builtin_amdgcn_s_setprio(0);
#pragma unroll
  for (int mt = 0; mt < 4; ++mt) bc[mt] = bn[mt];  // bc := bias(1)
  __syncthreads();  // drains tile-1 DMA

  const u16x8 ones = {0x3F80, 0x3F80, 0x3F80, 0x3F80,
                      0x3F80, 0x3F80, 0x3F80, 0x3F80};  // bf16 1.0
  f32x4 lacc = {};
  f32x4 oacc[4] = {};
  unsigned short* Vr = Vb[0];  // V(j-1)
  unsigned short* Vc = Vb[1];  // V(j)
  unsigned short* Vw = Vb[2];  // DMA target for V(j+1)

#pragma unroll 1
  for (int j = 1; j < 32; ++j) {
    const unsigned short* Kl = Kb[j & 1];            // K(j)
    unsigned short* Kw = Kb[(j + 1) & 1];            // target for K(j+1)
    if (j + 1 < 32) {  // issue DMA(j+1) + bias(j+1) loads
      int kt1 = (j + 1) * 64;
#pragma unroll
      for (int r = 0; r < 2; ++r) {
        int row = r * 32 + rt;
        int sc = ((gg ^ (row & 7)) << 3);
        g2lds16(&K[(size_t)(kt1 + row) * DK + sc], &Kw[r * 2048 + w * 512]);
        g2lds16(&V[(size_t)row * LL + kt1 + sc], &Vw[r * 2048 + w * 512]);
      }
#pragma unroll
      for (int mt = 0; mt < 4; ++mt)
        bn[mt] = *(const f16x4*)&BMF[(size_t)((j + 1) * 4 + mt) * 256];
    }

    __builtin_amdgcn_s_setprio(1);
    // softmax(j-1): pf from sP — INDEPENDENT of QK(j) below (interleavable)
    u16x8 pf[2];
    {
      unsigned L[4], H[4];
#pragma unroll
      for (int mt = 0; mt < 4; ++mt) {
        f32x4 p;
#pragma unroll
        for (int i = 0; i < 4; ++i) p[i] = fexp2(sP[mt][i]);
        u32x2 lw = __builtin_bit_cast(u32x2, cvt4(p));
        L[mt] = lw[0];  // keys 16mt+4qd+{0,1}
        H[mt] = lw[1];  // keys 16mt+4qd+{2,3}
      }
#pragma unroll
      for (int ks = 0; ks < 2; ++ks) {
        unsigned l0 = L[2 * ks], l1 = L[2 * ks + 1];
        unsigned h0 = H[2 * ks], h1 = H[2 * ks + 1];
        swap32(l0, l1); swap16(l0, l1);  // keys 8qd+{0,1} / +{4,5}
        swap32(h0, h1); swap16(h0, h1);  // keys 8qd+{2,3} / +{6,7}
        u32x4 pw = {l0, h0, l1, h1};
        pf[ks] = __builtin_bit_cast(u16x8, pw);
      }
    }
    // QK(j): K frags from Kl, bias(j) C-init -> sN
    f32x4 sN[4];
#pragma unroll
    for (int mt = 0; mt < 4; ++mt) {
      int row = 16 * mt + c;
      u16x8 k0f = *(const u16x8*)&Kl[row * 64 + ((qd ^ (c & 7)) << 3)];
      u16x8 k1f = *(const u16x8*)&Kl[row * 64 + (((4 + qd) ^ (c & 7)) << 3)];
      f16x4 b4 = bc[mt];
      f32x4 z = {(float)b4[0], (float)b4[1], (float)b4[2], (float)b4[3]};
      z = mfma16(k0f, qf[0], z);
      sN[mt] = mfma16(k1f, qf[1], z);
    }
    // PV(j-1) from Vr ; li via ones-MFMA
    lacc = mfma16(ones, pf[0], lacc);
    lacc = mfma16(ones, pf[1], lacc);
#pragma unroll
    for (int dt = 0; dt < 4; ++dt) {
      int row = 16 * dt + c;
      u16x8 v0f = *(const u16x8*)&Vr[row * 64 + ((qd ^ (c & 7)) << 3)];
      u16x8 v1f = *(const u16x8*)&Vr[row * 64 + (((4 + qd) ^ (c & 7)) << 3)];
      oacc[dt] = mfma16(v0f, pf[0], oacc[dt]);
      oacc[dt] = mfma16(v1f, pf[1], oacc[dt]);
    }
    __builtin_amdgcn_s_setprio(0);

    // rotate carried state
#pragma unroll
    for (int mt = 0; mt < 4; ++mt) { sP[mt] = sN[mt]; bc[mt] = bn[mt]; }
    unsigned short* tv = Vr; Vr = Vc; Vc = Vw; Vw = tv;
    __syncthreads();  // DMA(j+1) complete; all reads of this window done
  }

  // ---- epilogue: softmax + PV of tile 31 (V(31) now in Vr)
  {
    u16x8 pf[2];
    unsigned L[4], H[4];
#pragma unroll
    for (int mt = 0; mt < 4; ++mt) {
      f32x4 p;
#pragma unroll
      for (int i = 0; i < 4; ++i) p[i] = fexp2(sP[mt][i]);
      u32x2 lw = __builtin_bit_cast(u32x2, cvt4(p));
      L[mt] = lw[0]; H[mt] = lw[1];
    }
#pragma unroll
    for (int ks = 0; ks < 2; ++ks) {
      unsigned l0 = L[2 * ks], l1 = L[2 * ks + 1];
      unsigned h0 = H[2 * ks], h1 = H[2 * ks + 1];
      swap32(l0, l1); swap16(l0, l1);
      swap32(h0, h1); swap16(h0, h1);
      u32x4 pw = {l0, h0, l1, h1};
      pf[ks] = __builtin_bit_cast(u16x8, pw);
    }
    lacc = mfma16(ones, pf[0], lacc);
    lacc = mfma16(ones, pf[1], lacc);
#pragma unroll
    for (int dt = 0; dt < 4; ++dt) {
      int row = 16 * dt + c;
      u16x8 v0f = *(const u16x8*)&Vr[row * 64 + ((qd ^ (c & 7)) << 3)];
      u16x8 v1f = *(const u16x8*)&Vr[row * 64 + (((4 + qd) ^ (c & 7)) << 3)];
      oacc[dt] = mfma16(v0f, pf[0], oacc[dt]);
      oacc[dt] = mfma16(v1f, pf[1], oacc[dt]);
    }
  }

  // store O[b][q][h*64+d] bf16 (li full per-lane via ones-MFMA)
  {
    float rl = 1.f / lacc[0];
    size_t orow = ((size_t)b * LL + q0 + 16 * w + c) * DM + h * DK;
#pragma unroll
    for (int dt = 0; dt < 4; ++dt)
      *(u16x4*)&O[orow + 16 * dt + 4 * qd] = cvt4(oacc[dt] * rl);
  }
}

// ---------------------------------------------------------------------------
extern "C" void kernel_launch(void* const* d_in, const int* in_sizes, int n_in,
                              void* d_out, int out_size, void* d_ws, size_t ws_size,
                              hipStream_t stream) {
  (void)in_sizes; (void)n_in; (void)ws_size; (void)out_size;
  const float* q = (const float*)d_in[0];
  const float* k = (const float*)d_in[1];
  const float* v = (const float*)d_in[2];
  const int* mask = (const int*)d_in[3];
  const float* bias = (const float*)d_in[4];
  const float* w_qs = (const float*)d_in[5];
  const float* w_ks = (const float*)d_in[6];
  const float* w_vs = (const float*)d_in[7];
  const float* w_fc = (const float*)d_in[8];

  char* ws = (char*)d_ws;
  const size_t MB = 1024 * 1024;
  unsigned short* wT = (unsigned short*)(ws);              // [0,8M)
  f16* bmf = (f16*)(ws + 8 * MB);                          // [8,24M)
  unsigned short* qkvb = (unsigned short*)(ws + 24 * MB);  // [24,48M)
  unsigned short* qh = (unsigned short*)(ws + 48 * MB);    // [48,56M)
  unsigned short* kh = (unsigned short*)(ws + 56 * MB);    // [56,64M)
  unsigned short* vhT = (unsigned short*)(ws + 64 * MB);   // [64,72M)
  unsigned short* Obuf = (unsigned short*)(ws + 72 * MB);  // [72,80M)

  prep_all<<<dim3(18432), dim3(256), 0, stream>>>(w_qs, w_ks, w_vs, w_fc, wT,
                                                  mask, bias, bmf, q, k, v, qkvb);
  proj_gemm<<<dim3(768), 256, 0, stream>>>(qkvb, wT, qh, kh, vhT);
  attn_kern<<<dim3(1024), dim3(256), 0, stream>>>(qh, kh, vhT, bmf, Obuf);
  fc_gemm<<<dim3(256), 256, 0, stream>>>(Obuf, wT + (size_t)3 * DM * DM,
                                         (float*)d_out);
}

// Round 9
// 256.246 us; speedup vs baseline: 1.3775x; 1.0425x over previous
//
#include <hip/hip_runtime.h>
#include <cstddef>

#define DEV static __device__ __forceinline__

typedef float f32x4 __attribute__((ext_vector_type(4)));
typedef __bf16 bf16x8 __attribute__((ext_vector_type(8)));
typedef __bf16 bf16x4v __attribute__((ext_vector_type(4)));
typedef unsigned short u16x8 __attribute__((ext_vector_type(8)));
typedef unsigned short u16x4 __attribute__((ext_vector_type(4)));
typedef unsigned u32x2 __attribute__((ext_vector_type(2)));
typedef unsigned u32x4 __attribute__((ext_vector_type(4)));
typedef _Float16 f16;
typedef _Float16 f16x4 __attribute__((ext_vector_type(4)));

constexpr int BB = 2, LL = 2048, DM = 1024, NH = 16, DK = 64;
constexpr float LOG2E = 1.44269504f;

DEV unsigned short f2bf(float f) {
  unsigned u = __builtin_bit_cast(unsigned, f);
  u += 0x7fffu + ((u >> 16) & 1u);  // RNE
  return (unsigned short)(u >> 16);
}
DEV u16x4 cvt4(f32x4 v) {  // packed f32x4 -> bf16x4
  bf16x4v b = __builtin_convertvector(v, bf16x4v);
  return __builtin_bit_cast(u16x4, b);
}
DEV bf16x8 asbf(u16x8 v) { return __builtin_bit_cast(bf16x8, v); }
DEV f32x4 mfma16(u16x8 a, u16x8 b, f32x4 c) {
  return __builtin_amdgcn_mfma_f32_16x16x32_bf16(asbf(a), asbf(b), c, 0, 0, 0);
}
#if __has_builtin(__builtin_amdgcn_exp2f)
DEV float fexp2(float x) { return __builtin_amdgcn_exp2f(x); }
#else
DEV float fexp2(float x) { return exp2f(x); }
#endif
// cross-lane 16/32-row swaps (gfx950): used to rebuild PV fragments in-register
DEV void swap32(unsigned& a, unsigned& b) {
#if __has_builtin(__builtin_amdgcn_permlane32_swap)
  u32x2 r = __builtin_amdgcn_permlane32_swap(a, b, false, false);
  a = r[0]; b = r[1];
#else
  asm("v_permlane32_swap_b32 %0, %1" : "+v"(a), "+v"(b));
#endif
}
DEV void swap16(unsigned& a, unsigned& b) {
#if __has_builtin(__builtin_amdgcn_permlane16_swap)
  u32x2 r = __builtin_amdgcn_permlane16_swap(a, b, false, false);
  a = r[0]; b = r[1];
#else
  asm("v_permlane16_swap_b32 %0, %1" : "+v"(a), "+v"(b));
#endif
}
// async global->LDS, 16B/lane; lds dest wave-uniform base (+lane*16 by HW)
DEV void g2lds16(const void* g, void* l) {
  __builtin_amdgcn_global_load_lds(
      (const __attribute__((address_space(1))) unsigned int*)g,
      (__attribute__((address_space(3))) unsigned int*)l, 16, 0, 0);
}

// ---------------------------------------------------------------------------
// prep_all: prep_w + prep_cvt (prep_bm moved into the proj launch so it
// overlaps proj's compute-bound blocks in leftover CU capacity).
//  [0,4096):      prep_w  — transpose+cvt 4 weight mats -> bf16 W^T[N][K]
//  [4096,10240):  prep_cvt — q/k/v fp32 -> bf16
// ---------------------------------------------------------------------------
__global__ __launch_bounds__(256) void prep_all(
    const float* __restrict__ w0, const float* __restrict__ w1,
    const float* __restrict__ w2, const float* __restrict__ w3,
    unsigned short* __restrict__ wT, const float* __restrict__ s0,
    const float* __restrict__ s1, const float* __restrict__ s2,
    unsigned short* __restrict__ qkvb) {
  int f = blockIdx.x, t = threadIdx.x;
  if (f < 4096) {  // ---- prep_w
    __shared__ float tile[32][33];
    int z = f >> 10, rem = f & 1023;
    int k0 = (rem >> 5) * 32, n0 = (rem & 31) * 32;
    const float* W = (z == 0) ? w0 : (z == 1) ? w1 : (z == 2) ? w2 : w3;
    unsigned short* out = wT + (size_t)z * DM * DM;
    int tx = t & 31, ty = t >> 5;
#pragma unroll
    for (int p = 0; p < 4; p++)
      tile[ty + 8 * p][tx] = W[(size_t)(k0 + ty + 8 * p) * DM + n0 + tx];
    __syncthreads();
#pragma unroll
    for (int p = 0; p < 4; p++)
      out[(size_t)(n0 + ty + 8 * p) * DM + k0 + tx] = f2bf(tile[tx][ty + 8 * p]);
  } else {  // ---- prep_cvt
    int f3 = f - 4096;
    int z = f3 >> 11;
    const float* src = (z == 0) ? s0 : (z == 1) ? s1 : s2;
    size_t i = ((size_t)(f3 & 2047) * 256 + t) * 8;
    float4 a = *(const float4*)(src + i);
    float4 b = *(const float4*)(src + i + 4);
    u16x8 o;
    o[0] = f2bf(a.x); o[1] = f2bf(a.y); o[2] = f2bf(a.z); o[3] = f2bf(a.w);
    o[4] = f2bf(b.x); o[5] = f2bf(b.y); o[6] = f2bf(b.z); o[7] = f2bf(b.w);
    *(u16x8*)(qkvb + (size_t)z * (size_t)(BB * LL) * DM + i) = o;
  }
}

// ---------------------------------------------------------------------------
// GEMM core, m97 structure: 128x128 tile, BK=64, single-buffered 32 KB LDS,
// global_load_lds staging, 2 barriers/iter. Swizzle on the GLOBAL address
// side (gsw); LDS dest is linear base+lane*16.
// ---------------------------------------------------------------------------
template <int KITERS>
DEV void gemm_core(const unsigned short* __restrict__ A,
                   const unsigned short* __restrict__ BT,
                   unsigned short* Al, unsigned short* Bl,
                   int m0, int n0, int k0beg, int t, f32x4 (&acc)[4][4]) {
  int lane = t & 63, c = lane & 15, qd = lane >> 4;
  int w = t >> 6, wm = w >> 1, wn = w & 1;
  int r0 = t >> 3;               // 0..31; rows r0+32p keep same low 3 bits
  int gsw = (t & 7) ^ (r0 & 7);  // swizzled col-group for this thread

#pragma unroll 1
  for (int kk = 0; kk < KITERS; ++kk) {
    int k0 = k0beg + kk * 64;
#pragma unroll
    for (int p = 0; p < 4; ++p) {  // DMA: wave-uniform LDS base + lane*16
      g2lds16(&A[(size_t)(m0 + 32 * p + r0) * DM + k0 + 8 * gsw],
              &Al[p * 2048 + w * 512]);
      g2lds16(&BT[(size_t)(n0 + 32 * p + r0) * DM + k0 + 8 * gsw],
              &Bl[p * 2048 + w * 512]);
    }
    __syncthreads();  // drain DMA (vmcnt(0) folded into barrier)
#pragma unroll
    for (int ks = 0; ks < 2; ++ks) {
      u16x8 af[4], bfr[4];
#pragma unroll
      for (int mt = 0; mt < 4; ++mt)
        af[mt] = *(const u16x8*)&Al[(64 * wm + 16 * mt + c) * 64 +
                                    (((4 * ks + qd) ^ (c & 7)) << 3)];
#pragma unroll
      for (int nt = 0; nt < 4; ++nt)
        bfr[nt] = *(const u16x8*)&Bl[(64 * wn + 16 * nt + c) * 64 +
                                     (((4 * ks + qd) ^ (c & 7)) << 3)];
#pragma unroll
      for (int mt = 0; mt < 4; ++mt)
#pragma unroll
        for (int nt = 0; nt < 4; ++nt)
          acc[mt][nt] = mfma16(af[mt], bfr[nt], acc[mt][nt]);
    }
    __syncthreads();  // all reads done before next stage overwrites
  }
}

// ---------------------------------------------------------------------------
// proj_gemm + prep_bm fused launch. Blocks [0,768): q/k/v projections
// (3 blocks/CU via LDS 32 KB). Blocks [768,8960): prep_bm — HBM-bound,
// co-resident in the remaining 2x32 KB LDS slots per CU, so the bias/mask
// transform runs CONCURRENTLY with the compute-bound GEMM blocks.
// ---------------------------------------------------------------------------
__global__ __launch_bounds__(256, 3) void proj_gemm(
    const unsigned short* __restrict__ qkvb, const unsigned short* __restrict__ wT,
    unsigned short* __restrict__ qh, unsigned short* __restrict__ kh,
    unsigned short* __restrict__ vT, const int* __restrict__ mask,
    const float* __restrict__ bias, f16* __restrict__ bmf) {
  __shared__ unsigned short Al[128 * 64];  // 16 KiB
  __shared__ unsigned short Bl[128 * 64];  // 16 KiB
  int o = blockIdx.x, t = threadIdx.x;
  if (o >= 768) {  // ---- prep_bm (fragment order), overlapped
    int f2 = o - 768;
    int w = t >> 6, lane = t & 63;
    int bq = f2 >> 5;               // b*128 + qt
    int kt = (f2 & 31) * 4 + w;
    int b = bq >> 7, qt = bq & 127;
    int q = qt * 16 + (lane & 15);
    int k = kt * 16 + (lane >> 4) * 4;
    size_t src = ((size_t)b * LL + q) * LL + k;
    int4 mk = *(const int4*)(mask + src);
    float4 bs = *(const float4*)(bias + src);
    f16x4 oo;
    oo[0] = (f16)((mk.x == 0 ? -10000.f : bs.x) * LOG2E);
    oo[1] = (f16)((mk.y == 0 ? -10000.f : bs.y) * LOG2E);
    oo[2] = (f16)((mk.z == 0 ? -10000.f : bs.z) * LOG2E);
    oo[3] = (f16)((mk.w == 0 ? -10000.f : bs.w) * LOG2E);
    *(f16x4*)(bmf + ((size_t)bq * 128 + kt) * 256 + lane * 4) = oo;
    return;
  }
  // ---- projection GEMM
  int wg = (o & 7) * 96 + (o >> 3);  // bijective: 96 consecutive wgs per XCD
  int z = wg >> 8, rem = wg & 255;
  int m0 = (rem >> 3) * 128, n0 = (rem & 7) * 128;
  const unsigned short* A = qkvb + (size_t)z * BB * LL * DM;
  const unsigned short* BT = wT + (size_t)z * DM * DM;
  int lane = t & 63, c = lane & 15, qd = lane >> 4;
  int w = t >> 6, wm = w >> 1, wn = w & 1;
  f32x4 acc[4][4] = {};
  gemm_core<DM / 64>(A, BT, Al, Bl, m0, n0, 0, t, acc);

  if (z == 2) {  // V: per-head transposed vT[b][h][d][l]
#pragma unroll
    for (int mt = 0; mt < 4; ++mt)
#pragma unroll
      for (int nt = 0; nt < 4; ++nt) {
        int n = n0 + 64 * wn + 16 * nt + c;
        int h = n >> 6, d = n & 63;
        int m = m0 + 64 * wm + 16 * mt + 4 * qd;  // i=0..3 consecutive in l
        int b = m >> 11, l = m & 2047;
        *(u16x4*)&vT[(((size_t)b * NH + h) * DK + d) * LL + l] = cvt4(acc[mt][nt]);
      }
  } else {  // Q/K: head-split [b][h][l][d]; Q carries temperature*log2e
    unsigned short* Ch = z ? kh : qh;
    float scale = z ? 1.0f : 0.125f * LOG2E;
#pragma unroll
    for (int mt = 0; mt < 4; ++mt)
#pragma unroll
      for (int nt = 0; nt < 4; ++nt) {
        int n = n0 + 64 * wn + 16 * nt + c;
        int h = n >> 6, d = n & 63;
#pragma unroll
        for (int i = 0; i < 4; ++i) {
          int m = m0 + 64 * wm + 16 * mt + 4 * qd + i;
          int b = m >> 11, l = m & 2047;
          Ch[(((size_t)b * NH + h) * LL + l) * DK + d] = f2bf(acc[mt][nt][i] * scale);
        }
      }
  }
}

// ---------------------------------------------------------------------------
// final fc: 64x128 tiles -> 512 blocks = 2 blocks/CU, so a co-resident block
// overlaps the other's barrier drain (the m114 mechanism fc lacked at 1/CU).
// Single-K (16 iters), direct f32 stores. LDS 24 KB. XCD-chunked swizzle.
// ---------------------------------------------------------------------------
__global__ __launch_bounds__(256, 2) void fc_gemm(const unsigned short* __restrict__ A,
                                                  const unsigned short* __restrict__ BT,
                                                  float* __restrict__ C) {
  __shared__ unsigned short Al[64 * 64];   // 8 KiB
  __shared__ unsigned short Bl[128 * 64];  // 16 KiB
  int o = blockIdx.x;
  int wg = (o & 7) * 64 + (o >> 3);  // bijective: 64 consecutive wgs per XCD
  int m0 = (wg >> 3) * 64, n0 = (wg & 7) * 128;
  int t = threadIdx.x, lane = t & 63, c = lane & 15, qd = lane >> 4;
  int w = t >> 6, wm = w >> 1, wn = w & 1;
  int r0 = t >> 3, gsw = (t & 7) ^ (r0 & 7);
  f32x4 acc[2][4] = {};

#pragma unroll 1
  for (int kk = 0; kk < 16; ++kk) {
    int k0 = kk * 64;
#pragma unroll
    for (int p = 0; p < 2; ++p)
      g2lds16(&A[(size_t)(m0 + 32 * p + r0) * DM + k0 + 8 * gsw],
              &Al[p * 2048 + w * 512]);
#pragma unroll
    for (int p = 0; p < 4; ++p)
      g2lds16(&BT[(size_t)(n0 + 32 * p + r0) * DM + k0 + 8 * gsw],
              &Bl[p * 2048 + w * 512]);
    __syncthreads();
#pragma unroll
    for (int ks = 0; ks < 2; ++ks) {
      u16x8 af[2], bfr[4];
#pragma unroll
      for (int mt = 0; mt < 2; ++mt)
        af[mt] = *(const u16x8*)&Al[(32 * wm + 16 * mt + c) * 64 +
                                    (((4 * ks + qd) ^ (c & 7)) << 3)];
#pragma unroll
      for (int nt = 0; nt < 4; ++nt)
        bfr[nt] = *(const u16x8*)&Bl[(64 * wn + 16 * nt + c) * 64 +
                                     (((4 * ks + qd) ^ (c & 7)) << 3)];
#pragma unroll
      for (int mt = 0; mt < 2; ++mt)
#pragma unroll
        for (int nt = 0; nt < 4; ++nt)
          acc[mt][nt] = mfma16(af[mt], bfr[nt], acc[mt][nt]);
    }
    __syncthreads();
  }

#pragma unroll
  for (int mt = 0; mt < 2; ++mt)
#pragma unroll
    for (int nt = 0; nt < 4; ++nt) {
      int n = n0 + 64 * wn + 16 * nt + c;
#pragma unroll
      for (int i = 0; i < 4; ++i) {
        int m = m0 + 32 * wm + 16 * mt + 4 * qd + i;
        C[(size_t)m * DM + n] = acc[mt][nt][i];
      }
    }
}

// ---------------------------------------------------------------------------
// attn: SOFTWARE-PIPELINED flash loop (round-8 form, 58.6 us). Window j:
// softmax(j-1) ∥ QK(j) then PV(j-1); s carried in regs; V triple-buffered.
// 64 q-rows/block (4 waves x 16 q), TK=64, grid 1024 = 4 blk/CU (XCD swizzle),
// LDS 40 KB. bias as QK C-init; P^T in-register; li via ones-MFMA; setprio.
// ---------------------------------------------------------------------------
__global__ __launch_bounds__(256, 4) void attn_kern(
    const unsigned short* __restrict__ qh, const unsigned short* __restrict__ kh,
    const unsigned short* __restrict__ vT, const f16* __restrict__ bmf,
    unsigned short* __restrict__ O) {
  __shared__ unsigned short Kb[2][4096];  // 16 KiB swizzled [key][d]
  __shared__ unsigned short Vb[3][4096];  // 24 KiB swizzled [d][key], 3-deep

  int t = threadIdx.x, w = t >> 6, lane = t & 63, c = lane & 15, qd = lane >> 4;
  int o = blockIdx.x;
  int wg = (o & 7) * 128 + (o >> 3);  // bijective XCD chunking (1024%8==0)
  int x = wg & 31, h = (wg >> 5) & 15, b = wg >> 9;
  int q0 = x * 64;
  const unsigned short* Q = qh + (((size_t)b * NH + h) * LL + q0) * DK;
  const unsigned short* K = kh + ((size_t)b * NH + h) * LL * DK;
  const unsigned short* V = vT + ((size_t)b * NH + h) * DK * LL;
  const f16* BMF = bmf + (((size_t)b * 128 + x * 4 + w) * 128) * 256 + lane * 4;
  int rt = t >> 3, gg = t & 7;

  // ---- prologue: Q->Kb[1], K0->Kb[0], V0->Vb[0]; bias(0)->bc
  f16x4 bc[4], bn[4];
#pragma unroll
  for (int r = 0; r < 2; ++r) {
    int row = r * 32 + rt;
    int sc = ((gg ^ (row & 7)) << 3);
    g2lds16(&Q[(size_t)row * DK + sc], &Kb[1][r * 2048 + w * 512]);
    g2lds16(&K[(size_t)row * DK + sc], &Kb[0][r * 2048 + w * 512]);
    g2lds16(&V[(size_t)row * LL + sc], &Vb[0][r * 2048 + w * 512]);
  }
#pragma unroll
  for (int mt = 0; mt < 4; ++mt) bc[mt] = *(const f16x4*)&BMF[(size_t)mt * 256];
  __syncthreads();  // drains Q/K/V DMA

  u16x8 qf[2];  // wave w owns q rows 16w..16w+15
#pragma unroll
  for (int ks = 0; ks < 2; ++ks)
    qf[ks] = *(const u16x8*)&Kb[1][(16 * w + c) * 64 +
                                   (((4 * ks + qd) ^ (c & 7)) << 3)];
  __syncthreads();  // qf in regs before tile-1 DMA overwrites Kb[1]

  // ---- window 0: DMA tile 1; QK(0) with bias(0) C-init -> sP
  {
#pragma unroll
    for (int r = 0; r < 2; ++r) {
      int row = r * 32 + rt;
      int sc = ((gg ^ (row & 7)) << 3);
      g2lds16(&K[(size_t)(64 + row) * DK + sc], &Kb[1][r * 2048 + w * 512]);
      g2lds16(&V[(size_t)row * LL + 64 + sc], &Vb[1][r * 2048 + w * 512]);
    }
#pragma unroll
    for (int mt = 0; mt < 4; ++mt)
      bn[mt] = *(const f16x4*)&BMF[(size_t)(4 + mt) * 256];
  }
  f32x4 sP[4];
  __builtin_amdgcn_s_setprio(1);
#pragma unroll
  for (int mt = 0; mt < 4; ++mt) {
    int row = 16 * mt + c;
    u16x8 k0f = *(const u16x8*)&Kb[0][row * 64 + ((qd ^ (c & 7)) << 3)];
    u16x8 k1f = *(const u16x8*)&Kb[0][row * 64 + (((4 + qd) ^ (c & 7)) << 3)];
    f16x4 b4 = bc[mt];
    f32x4 z = {(float)b4[0], (float)b4[1], (float)b4[2], (float)b4[3]};
    z = mfma16(k0f, qf[0], z);
    sP[mt] = mfma16(k1f, qf[1], z);
  }
  __builtin_amdgcn_s_setprio(0);
#pragma unroll
  for (int mt = 0; mt < 4; ++mt) bc[mt] = bn[mt];  // bc := bias(1)
  __syncthreads();  // drains tile-1 DMA

  const u16x8 ones = {0x3F80, 0x3F80, 0x3F80, 0x3F80,
                      0x3F80, 0x3F80, 0x3F80, 0x3F80};  // bf16 1.0
  f32x4 lacc = {};
  f32x4 oacc[4] = {};
  unsigned short* Vr = Vb[0];  // V(j-1)
  unsigned short* Vc = Vb[1];  // V(j)
  unsigned short* Vw = Vb[2];  // DMA target for V(j+1)

#pragma unroll 1
  for (int j = 1; j < 32; ++j) {
    const unsigned short* Kl = Kb[j & 1];            // K(j)
    unsigned short* Kw = Kb[(j + 1) & 1];            // target for K(j+1)
    if (j + 1 < 32) {  // issue DMA(j+1) + bias(j+1) loads
      int kt1 = (j + 1) * 64;
#pragma unroll
      for (int r = 0; r < 2; ++r) {
        int row = r * 32 + rt;
        int sc = ((gg ^ (row & 7)) << 3);
        g2lds16(&K[(size_t)(kt1 + row) * DK + sc], &Kw[r * 2048 + w * 512]);
        g2lds16(&V[(size_t)row * LL + kt1 + sc], &Vw[r * 2048 + w * 512]);
      }
#pragma unroll
      for (int mt = 0; mt < 4; ++mt)
        bn[mt] = *(const f16x4*)&BMF[(size_t)((j + 1) * 4 + mt) * 256];
    }

    __builtin_amdgcn_s_setprio(1);
    // softmax(j-1): pf from sP — INDEPENDENT of QK(j) below (interleavable)
    u16x8 pf[2];
    {
      unsigned L[4], H[4];
#pragma unroll
      for (int mt = 0; mt < 4; ++mt) {
        f32x4 p;
#pragma unroll
        for (int i = 0; i < 4; ++i) p[i] = fexp2(sP[mt][i]);
        u32x2 lw = __builtin_bit_cast(u32x2, cvt4(p));
        L[mt] = lw[0];  // keys 16mt+4qd+{0,1}
        H[mt] = lw[1];  // keys 16mt+4qd+{2,3}
      }
#pragma unroll
      for (int ks = 0; ks < 2; ++ks) {
        unsigned l0 = L[2 * ks], l1 = L[2 * ks + 1];
        unsigned h0 = H[2 * ks], h1 = H[2 * ks + 1];
        swap32(l0, l1); swap16(l0, l1);  // keys 8qd+{0,1} / +{4,5}
        swap32(h0, h1); swap16(h0, h1);  // keys 8qd+{2,3} / +{6,7}
        u32x4 pw = {l0, h0, l1, h1};
        pf[ks] = __builtin_bit_cast(u16x8, pw);
      }
    }
    // QK(j): K frags from Kl, bias(j) C-init -> sN
    f32x4 sN[4];
#pragma unroll
    for (int mt = 0; mt < 4; ++mt) {
      int row = 16 * mt + c;
      u16x8 k0f = *(const u16x8*)&Kl[row * 64 + ((qd ^ (c & 7)) << 3)];
      u16x8 k1f = *(const u16x8*)&Kl[row * 64 + (((4 + qd) ^ (c & 7)) << 3)];
      f16x4 b4 = bc[mt];
      f32x4 z = {(float)b4[0], (float)b4[1], (float)b4[2], (float)b4[3]};
      z = mfma16(k0f, qf[0], z);
      sN[mt] = mfma16(k1f, qf[1], z);
    }
    // PV(j-1) from Vr ; li via ones-MFMA
    lacc = mfma16(ones, pf[0], lacc);
    lacc = mfma16(ones, pf[1], lacc);
#pragma unroll
    for (int dt = 0; dt < 4; ++dt) {
      int row = 16 * dt + c;
      u16x8 v0f = *(const u16x8*)&Vr[row * 64 + ((qd ^ (c & 7)) << 3)];
      u16x8 v1f = *(const u16x8*)&Vr[row * 64 + (((4 + qd) ^ (c & 7)) << 3)];
      oacc[dt] = mfma16(v0f, pf[0], oacc[dt]);
      oacc[dt] = mfma16(v1f, pf[1], oacc[dt]);
    }
    __builtin_amdgcn_s_setprio(0);

    // rotate carried state
#pragma unroll
    for (int mt = 0; mt < 4; ++mt) { sP[mt] = sN[mt]; bc[mt] = bn[mt]; }
    unsigned short* tv = Vr; Vr = Vc; Vc = Vw; Vw = tv;
    __syncthreads();  // DMA(j+1) complete; all reads of this window done
  }

  // ---- epilogue: softmax + PV of tile 31 (V(31) now in Vr)
  {
    u16x8 pf[2];
    unsigned L[4], H[4];
#pragma unroll
    for (int mt = 0; mt < 4; ++mt) {
      f32x4 p;
#pragma unroll
      for (int i = 0; i < 4; ++i) p[i] = fexp2(sP[mt][i]);
      u32x2 lw = __builtin_bit_cast(u32x2, cvt4(p));
      L[mt] = lw[0]; H[mt] = lw[1];
    }
#pragma unroll
    for (int ks = 0; ks < 2; ++ks) {
      unsigned l0 = L[2 * ks], l1 = L[2 * ks + 1];
      unsigned h0 = H[2 * ks], h1 = H[2 * ks + 1];
      swap32(l0, l1); swap16(l0, l1);
      swap32(h0, h1); swap16(h0, h1);
      u32x4 pw = {l0, h0, l1, h1};
      pf[ks] = __builtin_bit_cast(u16x8, pw);
    }
    lacc = mfma16(ones, pf[0], lacc);
    lacc = mfma16(ones, pf[1], lacc);
#pragma unroll
    for (int dt = 0; dt < 4; ++dt) {
      int row = 16 * dt + c;
      u16x8 v0f = *(const u16x8*)&Vr[row * 64 + ((qd ^ (c & 7)) << 3)];
      u16x8 v1f = *(const u16x8*)&Vr[row * 64 + (((4 + qd) ^ (c & 7)) << 3)];
      oacc[dt] = mfma16(v0f, pf[0], oacc[dt]);
      oacc[dt] = mfma16(v1f, pf[1], oacc[dt]);
    }
  }

  // store O[b][q][h*64+d] bf16 (li full per-lane via ones-MFMA)
  {
    float rl = 1.f / lacc[0];
    size_t orow = ((size_t)b * LL + q0 + 16 * w + c) * DM + h * DK;
#pragma unroll
    for (int dt = 0; dt < 4; ++dt)
      *(u16x4*)&O[orow + 16 * dt + 4 * qd] = cvt4(oacc[dt] * rl);
  }
}

// ---------------------------------------------------------------------------
extern "C" void kernel_launch(void* const* d_in, const int* in_sizes, int n_in,
                              void* d_out, int out_size, void* d_ws, size_t ws_size,
                              hipStream_t stream) {
  (void)in_sizes; (void)n_in; (void)ws_size; (void)out_size;
  const float* q = (const float*)d_in[0];
  const float* k = (const float*)d_in[1];
  const float* v = (const float*)d_in[2];
  const int* mask = (const int*)d_in[3];
  const float* bias = (const float*)d_in[4];
  const float* w_qs = (const float*)d_in[5];
  const float* w_ks = (const float*)d_in[6];
  const float* w_vs = (const float*)d_in[7];
  const float* w_fc = (const float*)d_in[8];

  char* ws = (char*)d_ws;
  const size_t MB = 1024 * 1024;
  unsigned short* wT = (unsigned short*)(ws);              // [0,8M)
  f16* bmf = (f16*)(ws + 8 * MB);                          // [8,24M)
  unsigned short* qkvb = (unsigned short*)(ws + 24 * MB);  // [24,48M)
  unsigned short* qh = (unsigned short*)(ws + 48 * MB);    // [48,56M)
  unsigned short* kh = (unsigned short*)(ws + 56 * MB);    // [56,64M)
  unsigned short* vhT = (unsigned short*)(ws + 64 * MB);   // [64,72M)
  unsigned short* Obuf = (unsigned short*)(ws + 72 * MB);  // [72,80M)

  prep_all<<<dim3(10240), dim3(256), 0, stream>>>(w_qs, w_ks, w_vs, w_fc, wT,
                                                  q, k, v, qkvb);
  proj_gemm<<<dim3(8960), 256, 0, stream>>>(qkvb, wT, qh, kh, vhT, mask, bias,
                                            bmf);
  attn_kern<<<dim3(1024), dim3(256), 0, stream>>>(qh, kh, vhT, bmf, Obuf);
  fc_gemm<<<dim3(512), 256, 0, stream>>>(Obuf, wT + (size_t)3 * DM * DM,
                                         (float*)d_out);
}